// Round 3
// baseline (2772.579 us; speedup 1.0000x reference)
//
#include <hip/hip_runtime.h>
#include <hip/hip_bf16.h>
#include <math.h>

#define NN 100000
#define EE 1250000
#define DD 64

// ---------------- degree count (int atomics) ----------------
__global__ __launch_bounds__(256) void deg_count(const int* __restrict__ row,
                                                 int* __restrict__ degi, int E) {
    int e = blockIdx.x * 256 + threadIdx.x;
    if (e >= E) return;
    atomicAdd(&degi[row[e]], 1);
}

// ---------------- scan step A: per-block exclusive scan + block sums ----------
__global__ __launch_bounds__(256) void scan_a(const int* __restrict__ degi,
                                              int* __restrict__ rowStart,
                                              int* __restrict__ bs, int N) {
    __shared__ int s[256];
    int tid = threadIdx.x;
    int i = blockIdx.x * 256 + tid;
    int v = (i < N) ? degi[i] : 0;
    s[tid] = v;
    __syncthreads();
    for (int off = 1; off < 256; off <<= 1) {
        int t = (tid >= off) ? s[tid - off] : 0;
        __syncthreads();
        s[tid] += t;
        __syncthreads();
    }
    if (i < N) rowStart[i] = s[tid] - v;   // exclusive
    if (tid == 255) bs[blockIdx.x] = s[255];
}

// ---------------- scan step B: exclusive scan of block sums (1 block) --------
__global__ __launch_bounds__(512) void scan_b(int* __restrict__ bs, int nb) {
    __shared__ int s[512];
    int tid = threadIdx.x;
    int v = (tid < nb) ? bs[tid] : 0;
    s[tid] = v;
    __syncthreads();
    for (int off = 1; off < 512; off <<= 1) {
        int t = (tid >= off) ? s[tid - off] : 0;
        __syncthreads();
        s[tid] += t;
        __syncthreads();
    }
    if (tid < nb) bs[tid] = s[tid] - v;    // exclusive
}

// ---------------- scan step C: add block offsets, set rowStart[N]=E ----------
__global__ __launch_bounds__(256) void scan_c(int* __restrict__ rowStart,
                                              const int* __restrict__ bs,
                                              int N, int E) {
    int i = blockIdx.x * 256 + threadIdx.x;
    if (i < N) rowStart[i] += bs[blockIdx.x];
    if (i == 0) rowStart[N] = E;
}

// ---------------- dis = deg^-0.5 (deg==0 -> 1) ----------------
__global__ __launch_bounds__(256) void dis_kernel(const int* __restrict__ degi,
                                                  float* __restrict__ dis, int N) {
    int i = blockIdx.x * 256 + threadIdx.x;
    if (i >= N) return;
    int d = degi[i];
    float df = (d == 0) ? 1.0f : (float)d;
    dis[i] = 1.0f / sqrtf(df);
}

// ---------------- scatter edges into CSR order, pack (val, col) --------------
__global__ __launch_bounds__(256) void scatter_kernel(const int* __restrict__ row,
                                                      const int* __restrict__ col,
                                                      const float* __restrict__ w,
                                                      const float* __restrict__ dis,
                                                      const int* __restrict__ rowStart,
                                                      int* __restrict__ cursor,
                                                      float2* __restrict__ ev, int E) {
    int e = blockIdx.x * 256 + threadIdx.x;
    if (e >= E) return;
    int r = row[e], c = col[e];
    int pos = rowStart[r] + atomicAdd(&cursor[r], 1);
    float v = dis[r] * w[e] * dis[c];
    ev[pos] = make_float2(v, __int_as_float(c));
}

// ---------------- scalar coefficients ----------------
// layout: [0]=al0*coef1, [1]=al0*coef2, [2..4]=L2 {tmp1_2,tmp2_2,tmp3}, [5..7]=L3
__global__ void coef_kernel(const float* __restrict__ ap, float* __restrict__ coef) {
    if (threadIdx.x != 0 || blockIdx.x != 0) return;
    const float a = 1.0f, b = 1.0f, l = -1.0f, r = 1.0f;
    float als[3];
    als[0] = tanhf(ap[0]);
    als[1] = tanhf(ap[1]);
    als[2] = tanhf(ap[2]);
    float coef1 = (a - b) * 0.5f - (a + b + 2.0f) * 0.5f * ((l + r) / (r - l));
    float coef2 = (a + b + 2.0f) / (r - l);
    coef[0] = als[0] * coef1;
    coef[1] = als[0] * coef2;
    for (int L = 2; L <= 3; ++L) {
        float Lf = (float)L;
        float coef_l     = 2.0f * Lf * (Lf + a + b) * (2.0f * Lf - 2.0f + a + b);
        float coef_lm1_1 = (2.0f * Lf + a + b - 1.0f) * (2.0f * Lf + a + b) * (2.0f * Lf + a + b - 2.0f);
        float coef_lm1_2 = (2.0f * Lf + a + b - 1.0f) * (a * a - b * b);
        float coef_lm2   = 2.0f * (Lf - 1.0f + a) * (Lf - 1.0f + b) * (2.0f * Lf + a + b);
        float tmp1   = als[L - 1] * (coef_lm1_1 / coef_l);
        float tmp2   = als[L - 1] * (coef_lm1_2 / coef_l);
        float tmp3   = als[L - 1] * als[L - 2] * (coef_lm2 / coef_l);
        float tmp1_2 = tmp1 * (2.0f / (r - l));
        float tmp2_2 = tmp1 * ((r + l) / (r - l)) + tmp2;
        int base = 2 + (L - 2) * 3;
        coef[base + 0] = tmp1_2;
        coef[base + 1] = tmp2_2;
        coef[base + 2] = tmp3;
    }
}

// ---------------- fused CSR SpMM + combine ----------------
// 16 lanes per row (one float4 each). MODE 0: out = c0*xm1 + c1*Ax
//                                     MODE 1: out = c0*Ax - c1*xm1 - c2*xm2
template <int MODE>
__global__ __launch_bounds__(256) void spmm_fused(const int* __restrict__ rowStart,
                                                  const float2* __restrict__ ev,
                                                  const float4* __restrict__ h,
                                                  const float4* __restrict__ xm1,
                                                  const float4* __restrict__ xm2,
                                                  float4* __restrict__ outp,
                                                  const float* __restrict__ coef,
                                                  int cbase, int N) {
    int t = blockIdx.x * 256 + threadIdx.x;
    int r = t >> 4;
    if (r >= N) return;
    int q = t & 15;
    int s0 = rowStart[r];
    int s1 = rowStart[r + 1];
    float4 acc = make_float4(0.f, 0.f, 0.f, 0.f);
    for (int j = s0; j < s1; ++j) {
        float2 e = ev[j];
        int c = __float_as_int(e.y);
        float4 hv = h[(size_t)c * 16 + q];
        acc.x += e.x * hv.x;
        acc.y += e.x * hv.y;
        acc.z += e.x * hv.z;
        acc.w += e.x * hv.w;
    }
    size_t oi = (size_t)r * 16 + q;
    float4 o;
    if (MODE == 0) {
        float c0 = coef[cbase], c1 = coef[cbase + 1];
        float4 m1 = xm1[oi];
        o.x = c0 * m1.x + c1 * acc.x;
        o.y = c0 * m1.y + c1 * acc.y;
        o.z = c0 * m1.z + c1 * acc.z;
        o.w = c0 * m1.w + c1 * acc.w;
    } else {
        float c0 = coef[cbase], c1 = coef[cbase + 1], c2 = coef[cbase + 2];
        float4 m1 = xm1[oi];
        float4 m2 = xm2[oi];
        o.x = c0 * acc.x - c1 * m1.x - c2 * m2.x;
        o.y = c0 * acc.y - c1 * m1.y - c2 * m2.y;
        o.z = c0 * acc.z - c1 * m1.z - c2 * m2.z;
        o.w = c0 * acc.w - c1 * m1.w - c2 * m2.w;
    }
    outp[oi] = o;
}

// ---------------- final fused GEMM: out = [x|A|B|C] @ W + bias ----------------
// Register-tiled: block 256 threads = 64x64 output tile, 4x4 per thread.
// K=256 staged in 4 segments of 64; each segment is a contiguous row-block of
// one input matrix (D=64). LDS: Xs[64][68] + Ws[64][64] = 33.8 KB -> 4 blk/CU.
#define LDX 68
__global__ __launch_bounds__(256) void final_gemm(const float* __restrict__ x0,
                                                  const float* __restrict__ x1,
                                                  const float* __restrict__ x2,
                                                  const float* __restrict__ x3,
                                                  const float* __restrict__ W,
                                                  const float* __restrict__ bias,
                                                  float* __restrict__ out) {
    __shared__ float Xs[64 * LDX];
    __shared__ float Ws[64 * 64];
    const int tid = threadIdx.x;
    const int tx = tid & 15;    // output col group (cols tx*4..+4)
    const int ty = tid >> 4;    // output row group (rows ty*4..+4)
    const int n0 = (int)blockIdx.x * 64;

    float acc[4][4];
    {
        float4 bv = ((const float4*)bias)[tx];
        #pragma unroll
        for (int i = 0; i < 4; ++i) {
            acc[i][0] = bv.x; acc[i][1] = bv.y; acc[i][2] = bv.z; acc[i][3] = bv.w;
        }
    }

    #pragma unroll
    for (int seg = 0; seg < 4; ++seg) {
        const float* p = (seg == 0) ? x0 : (seg == 1) ? x1 : (seg == 2) ? x2 : x3;
        // stage W chunk (rows seg*64..+64 of W = 64x64 floats, contiguous)
        {
            const float4* Wg = (const float4*)(W + seg * 64 * 64);
            float4* Ws4 = (float4*)Ws;
            #pragma unroll
            for (int j = 0; j < 4; ++j) Ws4[tid + 256 * j] = Wg[tid + 256 * j];
        }
        // stage X chunk (rows n0..n0+64 of matrix seg, contiguous, guarded)
        {
            const float4* Xg = (const float4*)p;
            #pragma unroll
            for (int j = 0; j < 4; ++j) {
                int idx = tid + 256 * j;         // 0..1023 float4s
                int r = idx >> 4, c4 = idx & 15;
                int gr = n0 + r;
                float4 v = (gr < NN) ? Xg[(size_t)gr * 16 + c4]
                                     : make_float4(0.f, 0.f, 0.f, 0.f);
                *((float4*)&Xs[r * LDX + c4 * 4]) = v;
            }
        }
        __syncthreads();
        // compute: k unrolled by 4 -> 8 ds_read_b128 per 64 FMAs
        #pragma unroll
        for (int k = 0; k < 64; k += 4) {
            float4 xf[4], wf[4];
            #pragma unroll
            for (int i = 0; i < 4; ++i)
                xf[i] = *((const float4*)&Xs[(ty * 4 + i) * LDX + k]);
            #pragma unroll
            for (int u = 0; u < 4; ++u)
                wf[u] = *((const float4*)&Ws[(k + u) * 64 + tx * 4]);
            #pragma unroll
            for (int i = 0; i < 4; ++i) {
                acc[i][0] += xf[i].x * wf[0].x + xf[i].y * wf[1].x
                           + xf[i].z * wf[2].x + xf[i].w * wf[3].x;
                acc[i][1] += xf[i].x * wf[0].y + xf[i].y * wf[1].y
                           + xf[i].z * wf[2].y + xf[i].w * wf[3].y;
                acc[i][2] += xf[i].x * wf[0].z + xf[i].y * wf[1].z
                           + xf[i].z * wf[2].z + xf[i].w * wf[3].z;
                acc[i][3] += xf[i].x * wf[0].w + xf[i].y * wf[1].w
                           + xf[i].z * wf[2].w + xf[i].w * wf[3].w;
            }
        }
        __syncthreads();
    }
    // store 4 rows x float4
    #pragma unroll
    for (int i = 0; i < 4; ++i) {
        int gr = n0 + ty * 4 + i;
        if (gr < NN) {
            float4 o = make_float4(acc[i][0], acc[i][1], acc[i][2], acc[i][3]);
            ((float4*)out)[(size_t)gr * 16 + tx] = o;
        }
    }
}

extern "C" void kernel_launch(void* const* d_in, const int* in_sizes, int n_in,
                              void* d_out, int out_size, void* d_ws, size_t ws_size,
                              hipStream_t stream) {
    const float* x  = (const float*)d_in[0];
    const int*   ei = (const int*)d_in[1];
    const float* ew = (const float*)d_in[2];
    const float* ap = (const float*)d_in[3];
    const float* lw = (const float*)d_in[4];
    const float* lb = (const float*)d_in[5];
    float* out = (float*)d_out;

    const int N = NN, E = EE;
    const int ND = N * DD;

    const int* row = ei;
    const int* col = ei + E;

    // workspace layout (big 16B-aligned buffers first)
    char* ws = (char*)d_ws;
    float* A   = (float*)ws;                               // 25.6 MB
    float* B   = (float*)(ws + (size_t)ND * 4);            // 25.6 MB
    float* C   = (float*)(ws + (size_t)ND * 8);            // 25.6 MB
    float2* ev = (float2*)(ws + (size_t)ND * 12);          // 10 MB
    char* sm   = ws + (size_t)ND * 12 + (size_t)E * 8;
    float* coef     = (float*)sm;                          // 256 B
    float* dis      = (float*)(sm + 256);                  // N floats
    int*   degi     = (int*)(sm + 256 + (size_t)N * 4);    // N ints (also cursor)
    int*   rowStart = (int*)(sm + 256 + (size_t)N * 8);    // N+1 ints
    int*   bs       = (int*)(sm + 256 + (size_t)N * 12 + 64); // 512 ints

    const int gridE  = (E + 255) / 256;      // 4883
    const int gridN  = (N + 255) / 256;      // 391
    const int gridSp = (N * 16) / 256;       // 6250 exact
    const int gridG  = (N + 63) / 64;        // 1563

    // ---- CSR build ----
    hipMemsetAsync(degi, 0, (size_t)N * 4, stream);
    deg_count<<<gridE, 256, 0, stream>>>(row, degi, E);
    coef_kernel<<<1, 64, 0, stream>>>(ap, coef);
    scan_a<<<gridN, 256, 0, stream>>>(degi, rowStart, bs, N);
    scan_b<<<1, 512, 0, stream>>>(bs, gridN);
    scan_c<<<gridN, 256, 0, stream>>>(rowStart, bs, N, E);
    dis_kernel<<<gridN, 256, 0, stream>>>(degi, dis, N);
    hipMemsetAsync(degi, 0, (size_t)N * 4, stream);        // reuse as cursor
    scatter_kernel<<<gridE, 256, 0, stream>>>(row, col, ew, dis, rowStart, degi, ev, E);

    // ---- L=1: A = c0*x + c1*(adj@x) ----
    spmm_fused<0><<<gridSp, 256, 0, stream>>>(rowStart, ev, (const float4*)x,
                                              (const float4*)x, (const float4*)x,
                                              (float4*)A, coef, 0, N);
    // ---- L=2: B = c0*(adj@A) - c1*A - c2*x ----
    spmm_fused<1><<<gridSp, 256, 0, stream>>>(rowStart, ev, (const float4*)A,
                                              (const float4*)A, (const float4*)x,
                                              (float4*)B, coef, 2, N);
    // ---- L=3: C = c0*(adj@B) - c1*B - c2*A ----
    spmm_fused<1><<<gridSp, 256, 0, stream>>>(rowStart, ev, (const float4*)B,
                                              (const float4*)B, (const float4*)A,
                                              (float4*)C, coef, 5, N);

    // ---- out = [x | A | B | C] @ W + b ----
    final_gemm<<<gridG, 256, 0, stream>>>(x, A, B, C, lw, lb, out);
}

// Round 4
// 822.259 us; speedup vs baseline: 3.3719x; 3.3719x over previous
//
#include <hip/hip_runtime.h>
#include <hip/hip_bf16.h>
#include <math.h>

#define NN 100000
#define EE 1250000
#define DD 64

// ---------------- degree count (int atomics) ----------------
__global__ __launch_bounds__(256) void deg_count(const int* __restrict__ row,
                                                 int* __restrict__ degi, int E) {
    int e = blockIdx.x * 256 + threadIdx.x;
    if (e >= E) return;
    atomicAdd(&degi[row[e]], 1);
}

// ---------------- scan step A: per-block exclusive scan + block sums ----------
__global__ __launch_bounds__(256) void scan_a(const int* __restrict__ degi,
                                              int* __restrict__ rowStart,
                                              int* __restrict__ bs, int N) {
    __shared__ int s[256];
    int tid = threadIdx.x;
    int i = blockIdx.x * 256 + tid;
    int v = (i < N) ? degi[i] : 0;
    s[tid] = v;
    __syncthreads();
    for (int off = 1; off < 256; off <<= 1) {
        int t = (tid >= off) ? s[tid - off] : 0;
        __syncthreads();
        s[tid] += t;
        __syncthreads();
    }
    if (i < N) rowStart[i] = s[tid] - v;   // exclusive
    if (tid == 255) bs[blockIdx.x] = s[255];
}

// ---------------- scan step B: exclusive scan of block sums (1 block) --------
__global__ __launch_bounds__(512) void scan_b(int* __restrict__ bs, int nb) {
    __shared__ int s[512];
    int tid = threadIdx.x;
    int v = (tid < nb) ? bs[tid] : 0;
    s[tid] = v;
    __syncthreads();
    for (int off = 1; off < 512; off <<= 1) {
        int t = (tid >= off) ? s[tid - off] : 0;
        __syncthreads();
        s[tid] += t;
        __syncthreads();
    }
    if (tid < nb) bs[tid] = s[tid] - v;    // exclusive
}

// ---------------- scan step C: add block offsets, set rowStart[N]=E ----------
__global__ __launch_bounds__(256) void scan_c(int* __restrict__ rowStart,
                                              const int* __restrict__ bs,
                                              int N, int E) {
    int i = blockIdx.x * 256 + threadIdx.x;
    if (i < N) rowStart[i] += bs[blockIdx.x];
    if (i == 0) rowStart[N] = E;
}

// ---------------- dis = deg^-0.5 (deg==0 -> 1) ----------------
__global__ __launch_bounds__(256) void dis_kernel(const int* __restrict__ degi,
                                                  float* __restrict__ dis, int N) {
    int i = blockIdx.x * 256 + threadIdx.x;
    if (i >= N) return;
    int d = degi[i];
    float df = (d == 0) ? 1.0f : (float)d;
    dis[i] = 1.0f / sqrtf(df);
}

// ---------------- scatter edges into CSR order, pack (val, col) --------------
__global__ __launch_bounds__(256) void scatter_kernel(const int* __restrict__ row,
                                                      const int* __restrict__ col,
                                                      const float* __restrict__ w,
                                                      const float* __restrict__ dis,
                                                      const int* __restrict__ rowStart,
                                                      int* __restrict__ cursor,
                                                      float2* __restrict__ ev, int E) {
    int e = blockIdx.x * 256 + threadIdx.x;
    if (e >= E) return;
    int r = row[e], c = col[e];
    int pos = rowStart[r] + atomicAdd(&cursor[r], 1);
    float v = dis[r] * w[e] * dis[c];
    ev[pos] = make_float2(v, __int_as_float(c));
}

// ---------------- scalar coefficients ----------------
// layout: [0]=al0*coef1, [1]=al0*coef2, [2..4]=L2 {tmp1_2,tmp2_2,tmp3}, [5..7]=L3
__global__ void coef_kernel(const float* __restrict__ ap, float* __restrict__ coef) {
    if (threadIdx.x != 0 || blockIdx.x != 0) return;
    const float a = 1.0f, b = 1.0f, l = -1.0f, r = 1.0f;
    float als[3];
    als[0] = tanhf(ap[0]);
    als[1] = tanhf(ap[1]);
    als[2] = tanhf(ap[2]);
    float coef1 = (a - b) * 0.5f - (a + b + 2.0f) * 0.5f * ((l + r) / (r - l));
    float coef2 = (a + b + 2.0f) / (r - l);
    coef[0] = als[0] * coef1;
    coef[1] = als[0] * coef2;
    for (int L = 2; L <= 3; ++L) {
        float Lf = (float)L;
        float coef_l     = 2.0f * Lf * (Lf + a + b) * (2.0f * Lf - 2.0f + a + b);
        float coef_lm1_1 = (2.0f * Lf + a + b - 1.0f) * (2.0f * Lf + a + b) * (2.0f * Lf + a + b - 2.0f);
        float coef_lm1_2 = (2.0f * Lf + a + b - 1.0f) * (a * a - b * b);
        float coef_lm2   = 2.0f * (Lf - 1.0f + a) * (Lf - 1.0f + b) * (2.0f * Lf + a + b);
        float tmp1   = als[L - 1] * (coef_lm1_1 / coef_l);
        float tmp2   = als[L - 1] * (coef_lm1_2 / coef_l);
        float tmp3   = als[L - 1] * als[L - 2] * (coef_lm2 / coef_l);
        float tmp1_2 = tmp1 * (2.0f / (r - l));
        float tmp2_2 = tmp1 * ((r + l) / (r - l)) + tmp2;
        int base = 2 + (L - 2) * 3;
        coef[base + 0] = tmp1_2;
        coef[base + 1] = tmp2_2;
        coef[base + 2] = tmp3;
    }
}

// ---------------- fused CSR SpMM + combine ----------------
// 16 lanes per row (one float4 each). MODE 0: out = c0*xm1 + c1*Ax
//                                     MODE 1: out = c0*Ax - c1*xm1 - c2*xm2
template <int MODE>
__global__ __launch_bounds__(256) void spmm_fused(const int* __restrict__ rowStart,
                                                  const float2* __restrict__ ev,
                                                  const float4* __restrict__ h,
                                                  const float4* __restrict__ xm1,
                                                  const float4* __restrict__ xm2,
                                                  float4* __restrict__ outp,
                                                  const float* __restrict__ coef,
                                                  int cbase, int N) {
    int t = blockIdx.x * 256 + threadIdx.x;
    int r = t >> 4;
    if (r >= N) return;
    int q = t & 15;
    int s0 = rowStart[r];
    int s1 = rowStart[r + 1];
    float4 acc = make_float4(0.f, 0.f, 0.f, 0.f);
    for (int j = s0; j < s1; ++j) {
        float2 e = ev[j];
        int c = __float_as_int(e.y);
        float4 hv = h[(size_t)c * 16 + q];
        acc.x += e.x * hv.x;
        acc.y += e.x * hv.y;
        acc.z += e.x * hv.z;
        acc.w += e.x * hv.w;
    }
    size_t oi = (size_t)r * 16 + q;
    float4 o;
    if (MODE == 0) {
        float c0 = coef[cbase], c1 = coef[cbase + 1];
        float4 m1 = xm1[oi];
        o.x = c0 * m1.x + c1 * acc.x;
        o.y = c0 * m1.y + c1 * acc.y;
        o.z = c0 * m1.z + c1 * acc.z;
        o.w = c0 * m1.w + c1 * acc.w;
    } else {
        float c0 = coef[cbase], c1 = coef[cbase + 1], c2 = coef[cbase + 2];
        float4 m1 = xm1[oi];
        float4 m2 = xm2[oi];
        o.x = c0 * acc.x - c1 * m1.x - c2 * m2.x;
        o.y = c0 * acc.y - c1 * m1.y - c2 * m2.y;
        o.z = c0 * acc.z - c1 * m1.z - c2 * m2.z;
        o.w = c0 * acc.w - c1 * m1.w - c2 * m2.w;
    }
    outp[oi] = o;
}

// ---------------- final fused GEMM: out = [x|A|B|C] @ W + bias ----------------
// Register-tiled: block 256 threads = 64x64 output tile, 4x4 per thread.
// K=256 staged in 4 segments of 64. LDS: Xs[64][68] + Ws[64][64] = 33.8 KB.
// seg loop is `#pragma unroll 1` — R3 showed full unroll hoists 32 float4
// staging loads above the barriers -> 256 VGPR -> 5.7 GB scratch spill.
// __launch_bounds__(256,4) caps the allocator at 128 VGPR (4 blocks/CU).
#define LDX 68
__global__ __launch_bounds__(256, 4) void final_gemm(const float* __restrict__ x0,
                                                     const float* __restrict__ x1,
                                                     const float* __restrict__ x2,
                                                     const float* __restrict__ x3,
                                                     const float* __restrict__ W,
                                                     const float* __restrict__ bias,
                                                     float* __restrict__ out) {
    __shared__ float Xs[64 * LDX];
    __shared__ float Ws[64 * 64];
    const int tid = threadIdx.x;
    const int tx = tid & 15;    // output col group (cols tx*4..+4)
    const int ty = tid >> 4;    // output row group (rows ty*4..+4)
    const int n0 = (int)blockIdx.x * 64;

    float acc[4][4];
    {
        float4 bv = ((const float4*)bias)[tx];
        #pragma unroll
        for (int i = 0; i < 4; ++i) {
            acc[i][0] = bv.x; acc[i][1] = bv.y; acc[i][2] = bv.z; acc[i][3] = bv.w;
        }
    }

    #pragma unroll 1
    for (int seg = 0; seg < 4; ++seg) {
        const float* p = (seg == 0) ? x0 : (seg == 1) ? x1 : (seg == 2) ? x2 : x3;
        // stage W chunk (rows seg*64..+64 of W = 64x64 floats, contiguous)
        {
            const float4* Wg = (const float4*)(W + seg * 64 * 64);
            float4* Ws4 = (float4*)Ws;
            #pragma unroll
            for (int j = 0; j < 4; ++j) Ws4[tid + 256 * j] = Wg[tid + 256 * j];
        }
        // stage X chunk (rows n0..n0+64 of matrix seg, contiguous, guarded)
        {
            const float4* Xg = (const float4*)p;
            #pragma unroll
            for (int j = 0; j < 4; ++j) {
                int idx = tid + 256 * j;         // 0..1023 float4s
                int r = idx >> 4, c4 = idx & 15;
                int gr = n0 + r;
                float4 v = (gr < NN) ? Xg[(size_t)gr * 16 + c4]
                                     : make_float4(0.f, 0.f, 0.f, 0.f);
                *((float4*)&Xs[r * LDX + c4 * 4]) = v;
            }
        }
        __syncthreads();
        // compute: k unrolled by 4 -> 8 ds_read_b128 per 64 FMAs
        #pragma unroll
        for (int k = 0; k < 64; k += 4) {
            float4 xf[4], wf[4];
            #pragma unroll
            for (int i = 0; i < 4; ++i)
                xf[i] = *((const float4*)&Xs[(ty * 4 + i) * LDX + k]);
            #pragma unroll
            for (int u = 0; u < 4; ++u)
                wf[u] = *((const float4*)&Ws[(k + u) * 64 + tx * 4]);
            #pragma unroll
            for (int i = 0; i < 4; ++i) {
                acc[i][0] += xf[i].x * wf[0].x + xf[i].y * wf[1].x
                           + xf[i].z * wf[2].x + xf[i].w * wf[3].x;
                acc[i][1] += xf[i].x * wf[0].y + xf[i].y * wf[1].y
                           + xf[i].z * wf[2].y + xf[i].w * wf[3].y;
                acc[i][2] += xf[i].x * wf[0].z + xf[i].y * wf[1].z
                           + xf[i].z * wf[2].z + xf[i].w * wf[3].z;
                acc[i][3] += xf[i].x * wf[0].w + xf[i].y * wf[1].w
                           + xf[i].z * wf[2].w + xf[i].w * wf[3].w;
            }
        }
        __syncthreads();
    }
    // store 4 rows x float4
    #pragma unroll
    for (int i = 0; i < 4; ++i) {
        int gr = n0 + ty * 4 + i;
        if (gr < NN) {
            float4 o = make_float4(acc[i][0], acc[i][1], acc[i][2], acc[i][3]);
            ((float4*)out)[(size_t)gr * 16 + tx] = o;
        }
    }
}

extern "C" void kernel_launch(void* const* d_in, const int* in_sizes, int n_in,
                              void* d_out, int out_size, void* d_ws, size_t ws_size,
                              hipStream_t stream) {
    const float* x  = (const float*)d_in[0];
    const int*   ei = (const int*)d_in[1];
    const float* ew = (const float*)d_in[2];
    const float* ap = (const float*)d_in[3];
    const float* lw = (const float*)d_in[4];
    const float* lb = (const float*)d_in[5];
    float* out = (float*)d_out;

    const int N = NN, E = EE;
    const int ND = N * DD;

    const int* row = ei;
    const int* col = ei + E;

    // workspace layout (big 16B-aligned buffers first)
    char* ws = (char*)d_ws;
    float* A   = (float*)ws;                               // 25.6 MB
    float* B   = (float*)(ws + (size_t)ND * 4);            // 25.6 MB
    float* C   = (float*)(ws + (size_t)ND * 8);            // 25.6 MB
    float2* ev = (float2*)(ws + (size_t)ND * 12);          // 10 MB
    char* sm   = ws + (size_t)ND * 12 + (size_t)E * 8;
    float* coef     = (float*)sm;                          // 256 B
    float* dis      = (float*)(sm + 256);                  // N floats
    int*   degi     = (int*)(sm + 256 + (size_t)N * 4);    // N ints (also cursor)
    int*   rowStart = (int*)(sm + 256 + (size_t)N * 8);    // N+1 ints
    int*   bs       = (int*)(sm + 256 + (size_t)N * 12 + 64); // 512 ints

    const int gridE  = (E + 255) / 256;      // 4883
    const int gridN  = (N + 255) / 256;      // 391
    const int gridSp = (N * 16) / 256;       // 6250 exact
    const int gridG  = (N + 63) / 64;        // 1563

    // ---- CSR build ----
    hipMemsetAsync(degi, 0, (size_t)N * 4, stream);
    deg_count<<<gridE, 256, 0, stream>>>(row, degi, E);
    coef_kernel<<<1, 64, 0, stream>>>(ap, coef);
    scan_a<<<gridN, 256, 0, stream>>>(degi, rowStart, bs, N);
    scan_b<<<1, 512, 0, stream>>>(bs, gridN);
    scan_c<<<gridN, 256, 0, stream>>>(rowStart, bs, N, E);
    dis_kernel<<<gridN, 256, 0, stream>>>(degi, dis, N);
    hipMemsetAsync(degi, 0, (size_t)N * 4, stream);        // reuse as cursor
    scatter_kernel<<<gridE, 256, 0, stream>>>(row, col, ew, dis, rowStart, degi, ev, E);

    // ---- L=1: A = c0*x + c1*(adj@x) ----
    spmm_fused<0><<<gridSp, 256, 0, stream>>>(rowStart, ev, (const float4*)x,
                                              (const float4*)x, (const float4*)x,
                                              (float4*)A, coef, 0, N);
    // ---- L=2: B = c0*(adj@A) - c1*A - c2*x ----
    spmm_fused<1><<<gridSp, 256, 0, stream>>>(rowStart, ev, (const float4*)A,
                                              (const float4*)A, (const float4*)x,
                                              (float4*)B, coef, 2, N);
    // ---- L=3: C = c0*(adj@B) - c1*B - c2*A ----
    spmm_fused<1><<<gridSp, 256, 0, stream>>>(rowStart, ev, (const float4*)B,
                                              (const float4*)B, (const float4*)A,
                                              (float4*)C, coef, 5, N);

    // ---- out = [x | A | B | C] @ W + b ----
    final_gemm<<<gridG, 256, 0, stream>>>(x, A, B, C, lw, lb, out);
}

// Round 5
// 436.728 us; speedup vs baseline: 6.3485x; 1.8828x over previous
//
#include <hip/hip_runtime.h>
#include <hip/hip_bf16.h>
#include <math.h>

#define NN 100000
#define EE 1250000
#define DD 64

// ---------------- degree count (int atomics) ----------------
__global__ __launch_bounds__(256) void deg_count(const int* __restrict__ row,
                                                 int* __restrict__ degi, int E) {
    int e = blockIdx.x * 256 + threadIdx.x;
    if (e >= E) return;
    atomicAdd(&degi[row[e]], 1);
}

// ---------------- scan step A: per-block exclusive scan + block sums ----------
__global__ __launch_bounds__(256) void scan_a(const int* __restrict__ degi,
                                              int* __restrict__ rowStart,
                                              int* __restrict__ bs, int N) {
    __shared__ int s[256];
    int tid = threadIdx.x;
    int i = blockIdx.x * 256 + tid;
    int v = (i < N) ? degi[i] : 0;
    s[tid] = v;
    __syncthreads();
    for (int off = 1; off < 256; off <<= 1) {
        int t = (tid >= off) ? s[tid - off] : 0;
        __syncthreads();
        s[tid] += t;
        __syncthreads();
    }
    if (i < N) rowStart[i] = s[tid] - v;   // exclusive
    if (tid == 255) bs[blockIdx.x] = s[255];
}

// ---------------- scan step B: exclusive scan of block sums (1 block) --------
__global__ __launch_bounds__(512) void scan_b(int* __restrict__ bs, int nb) {
    __shared__ int s[512];
    int tid = threadIdx.x;
    int v = (tid < nb) ? bs[tid] : 0;
    s[tid] = v;
    __syncthreads();
    for (int off = 1; off < 512; off <<= 1) {
        int t = (tid >= off) ? s[tid - off] : 0;
        __syncthreads();
        s[tid] += t;
        __syncthreads();
    }
    if (tid < nb) bs[tid] = s[tid] - v;    // exclusive
}

// ---------------- scan step C: add block offsets, set rowStart[N]=E ----------
__global__ __launch_bounds__(256) void scan_c(int* __restrict__ rowStart,
                                              const int* __restrict__ bs,
                                              int N, int E) {
    int i = blockIdx.x * 256 + threadIdx.x;
    if (i < N) rowStart[i] += bs[blockIdx.x];
    if (i == 0) rowStart[N] = E;
}

// ---------------- dis = deg^-0.5 (deg==0 -> 1) ----------------
__global__ __launch_bounds__(256) void dis_kernel(const int* __restrict__ degi,
                                                  float* __restrict__ dis, int N) {
    int i = blockIdx.x * 256 + threadIdx.x;
    if (i >= N) return;
    int d = degi[i];
    float df = (d == 0) ? 1.0f : (float)d;
    dis[i] = 1.0f / sqrtf(df);
}

// ---------------- scatter edges into CSR order, pack (val, col) --------------
__global__ __launch_bounds__(256) void scatter_kernel(const int* __restrict__ row,
                                                      const int* __restrict__ col,
                                                      const float* __restrict__ w,
                                                      const float* __restrict__ dis,
                                                      const int* __restrict__ rowStart,
                                                      int* __restrict__ cursor,
                                                      float2* __restrict__ ev, int E) {
    int e = blockIdx.x * 256 + threadIdx.x;
    if (e >= E) return;
    int r = row[e], c = col[e];
    int pos = rowStart[r] + atomicAdd(&cursor[r], 1);
    float v = dis[r] * w[e] * dis[c];
    ev[pos] = make_float2(v, __int_as_float(c));
}

// ---------------- scalar coefficients ----------------
// layout: [0]=al0*coef1, [1]=al0*coef2, [2..4]=L2 {tmp1_2,tmp2_2,tmp3}, [5..7]=L3
__global__ void coef_kernel(const float* __restrict__ ap, float* __restrict__ coef) {
    if (threadIdx.x != 0 || blockIdx.x != 0) return;
    const float a = 1.0f, b = 1.0f, l = -1.0f, r = 1.0f;
    float als[3];
    als[0] = tanhf(ap[0]);
    als[1] = tanhf(ap[1]);
    als[2] = tanhf(ap[2]);
    float coef1 = (a - b) * 0.5f - (a + b + 2.0f) * 0.5f * ((l + r) / (r - l));
    float coef2 = (a + b + 2.0f) / (r - l);
    coef[0] = als[0] * coef1;
    coef[1] = als[0] * coef2;
    for (int L = 2; L <= 3; ++L) {
        float Lf = (float)L;
        float coef_l     = 2.0f * Lf * (Lf + a + b) * (2.0f * Lf - 2.0f + a + b);
        float coef_lm1_1 = (2.0f * Lf + a + b - 1.0f) * (2.0f * Lf + a + b) * (2.0f * Lf + a + b - 2.0f);
        float coef_lm1_2 = (2.0f * Lf + a + b - 1.0f) * (a * a - b * b);
        float coef_lm2   = 2.0f * (Lf - 1.0f + a) * (Lf - 1.0f + b) * (2.0f * Lf + a + b);
        float tmp1   = als[L - 1] * (coef_lm1_1 / coef_l);
        float tmp2   = als[L - 1] * (coef_lm1_2 / coef_l);
        float tmp3   = als[L - 1] * als[L - 2] * (coef_lm2 / coef_l);
        float tmp1_2 = tmp1 * (2.0f / (r - l));
        float tmp2_2 = tmp1 * ((r + l) / (r - l)) + tmp2;
        int base = 2 + (L - 2) * 3;
        coef[base + 0] = tmp1_2;
        coef[base + 1] = tmp2_2;
        coef[base + 2] = tmp3;
    }
}

// ---------------- fused CSR SpMM + combine ----------------
// 16 lanes per row (one float4 each). MODE 0: out = c0*xm1 + c1*Ax
//                                     MODE 1: out = c0*Ax - c1*xm1 - c2*xm2
template <int MODE>
__global__ __launch_bounds__(256) void spmm_fused(const int* __restrict__ rowStart,
                                                  const float2* __restrict__ ev,
                                                  const float4* __restrict__ h,
                                                  const float4* __restrict__ xm1,
                                                  const float4* __restrict__ xm2,
                                                  float4* __restrict__ outp,
                                                  const float* __restrict__ coef,
                                                  int cbase, int N) {
    int t = blockIdx.x * 256 + threadIdx.x;
    int r = t >> 4;
    if (r >= N) return;
    int q = t & 15;
    int s0 = rowStart[r];
    int s1 = rowStart[r + 1];
    float4 acc = make_float4(0.f, 0.f, 0.f, 0.f);
    for (int j = s0; j < s1; ++j) {
        float2 e = ev[j];
        int c = __float_as_int(e.y);
        float4 hv = h[(size_t)c * 16 + q];
        acc.x += e.x * hv.x;
        acc.y += e.x * hv.y;
        acc.z += e.x * hv.z;
        acc.w += e.x * hv.w;
    }
    size_t oi = (size_t)r * 16 + q;
    float4 o;
    if (MODE == 0) {
        float c0 = coef[cbase], c1 = coef[cbase + 1];
        float4 m1 = xm1[oi];
        o.x = c0 * m1.x + c1 * acc.x;
        o.y = c0 * m1.y + c1 * acc.y;
        o.z = c0 * m1.z + c1 * acc.z;
        o.w = c0 * m1.w + c1 * acc.w;
    } else {
        float c0 = coef[cbase], c1 = coef[cbase + 1], c2 = coef[cbase + 2];
        float4 m1 = xm1[oi];
        float4 m2 = xm2[oi];
        o.x = c0 * acc.x - c1 * m1.x - c2 * m2.x;
        o.y = c0 * acc.y - c1 * m1.y - c2 * m2.y;
        o.z = c0 * acc.z - c1 * m1.z - c2 * m2.z;
        o.w = c0 * acc.w - c1 * m1.w - c2 * m2.w;
    }
    outp[oi] = o;
}

// ---------------- final fused GEMM: out = [x|A|B|C] @ W + bias ----------------
// Register-tiled: block 256 threads = 64x64 output tile, 4x4 per thread.
// Thread (tx,ty) owns rows {ty, ty+16, ty+32, ty+48} (strided!) and cols
// tx*4..tx*4+3. Strided row ownership makes the 16 xf addresses per
// ds_read_b128 span 8 bank-quads (2-way = free); the old 4*ty+i mapping hit
// only 2 quads (8-way conflict). LDX=68 keeps rows 16B-aligned (272 B).
// seg loop stays `#pragma unroll 1` (R3: full unroll -> 256 VGPR spill);
// NO min-waves clamp (R4: __launch_bounds__(256,4) forced 64 VGPR -> spill).
// k-loop unrolled x2: ~96 live VGPRs, no spill.
#define LDX 68
__global__ __launch_bounds__(256) void final_gemm(const float* __restrict__ x0,
                                                  const float* __restrict__ x1,
                                                  const float* __restrict__ x2,
                                                  const float* __restrict__ x3,
                                                  const float* __restrict__ W,
                                                  const float* __restrict__ bias,
                                                  float* __restrict__ out) {
    __shared__ float Xs[64 * LDX];
    __shared__ float Ws[64 * 64];
    const int tid = threadIdx.x;
    const int tx = tid & 15;    // output col group (cols tx*4..+4)
    const int ty = tid >> 4;    // output row base (rows ty+16*i)
    const int n0 = (int)blockIdx.x * 64;

    float acc[4][4];
    {
        float4 bv = ((const float4*)bias)[tx];
        #pragma unroll
        for (int i = 0; i < 4; ++i) {
            acc[i][0] = bv.x; acc[i][1] = bv.y; acc[i][2] = bv.z; acc[i][3] = bv.w;
        }
    }

    #pragma unroll 1
    for (int seg = 0; seg < 4; ++seg) {
        const float* p = (seg == 0) ? x0 : (seg == 1) ? x1 : (seg == 2) ? x2 : x3;
        // stage W chunk (rows seg*64..+64 of W = 64x64 floats, contiguous)
        {
            const float4* Wg = (const float4*)(W + seg * 64 * 64);
            float4* Ws4 = (float4*)Ws;
            #pragma unroll
            for (int j = 0; j < 4; ++j) Ws4[tid + 256 * j] = Wg[tid + 256 * j];
        }
        // stage X chunk (rows n0..n0+64 of matrix seg, contiguous, guarded)
        {
            const float4* Xg = (const float4*)p;
            #pragma unroll
            for (int j = 0; j < 4; ++j) {
                int idx = tid + 256 * j;         // 0..1023 float4s
                int r = idx >> 4, c4 = idx & 15;
                int gr = n0 + r;
                float4 v = (gr < NN) ? Xg[(size_t)gr * 16 + c4]
                                     : make_float4(0.f, 0.f, 0.f, 0.f);
                *((float4*)&Xs[r * LDX + c4 * 4]) = v;
            }
        }
        __syncthreads();
        // compute: 2 k-groups per iteration -> 16 ds_read_b128 per 128 FMAs
        #pragma unroll 2
        for (int k = 0; k < 64; k += 4) {
            float4 xf[4], wf[4];
            #pragma unroll
            for (int i = 0; i < 4; ++i)
                xf[i] = *((const float4*)&Xs[(ty + 16 * i) * LDX + k]);
            #pragma unroll
            for (int u = 0; u < 4; ++u)
                wf[u] = *((const float4*)&Ws[(k + u) * 64 + tx * 4]);
            #pragma unroll
            for (int i = 0; i < 4; ++i) {
                acc[i][0] += xf[i].x * wf[0].x + xf[i].y * wf[1].x
                           + xf[i].z * wf[2].x + xf[i].w * wf[3].x;
                acc[i][1] += xf[i].x * wf[0].y + xf[i].y * wf[1].y
                           + xf[i].z * wf[2].y + xf[i].w * wf[3].y;
                acc[i][2] += xf[i].x * wf[0].z + xf[i].y * wf[1].z
                           + xf[i].z * wf[2].z + xf[i].w * wf[3].z;
                acc[i][3] += xf[i].x * wf[0].w + xf[i].y * wf[1].w
                           + xf[i].z * wf[2].w + xf[i].w * wf[3].w;
            }
        }
        __syncthreads();
    }
    // store 4 strided rows x float4 (coalesced: 16 lanes cover 256 B per row)
    #pragma unroll
    for (int i = 0; i < 4; ++i) {
        int gr = n0 + ty + 16 * i;
        if (gr < NN) {
            float4 o = make_float4(acc[i][0], acc[i][1], acc[i][2], acc[i][3]);
            ((float4*)out)[(size_t)gr * 16 + tx] = o;
        }
    }
}

extern "C" void kernel_launch(void* const* d_in, const int* in_sizes, int n_in,
                              void* d_out, int out_size, void* d_ws, size_t ws_size,
                              hipStream_t stream) {
    const float* x  = (const float*)d_in[0];
    const int*   ei = (const int*)d_in[1];
    const float* ew = (const float*)d_in[2];
    const float* ap = (const float*)d_in[3];
    const float* lw = (const float*)d_in[4];
    const float* lb = (const float*)d_in[5];
    float* out = (float*)d_out;

    const int N = NN, E = EE;
    const int ND = N * DD;

    const int* row = ei;
    const int* col = ei + E;

    // workspace layout (big 16B-aligned buffers first)
    char* ws = (char*)d_ws;
    float* A   = (float*)ws;                               // 25.6 MB
    float* B   = (float*)(ws + (size_t)ND * 4);            // 25.6 MB
    float* C   = (float*)(ws + (size_t)ND * 8);            // 25.6 MB
    float2* ev = (float2*)(ws + (size_t)ND * 12);          // 10 MB
    char* sm   = ws + (size_t)ND * 12 + (size_t)E * 8;
    float* coef     = (float*)sm;                          // 256 B
    float* dis      = (float*)(sm + 256);                  // N floats
    int*   degi     = (int*)(sm + 256 + (size_t)N * 4);    // N ints (also cursor)
    int*   rowStart = (int*)(sm + 256 + (size_t)N * 8);    // N+1 ints
    int*   bs       = (int*)(sm + 256 + (size_t)N * 12 + 64); // 512 ints

    const int gridE  = (E + 255) / 256;      // 4883
    const int gridN  = (N + 255) / 256;      // 391
    const int gridSp = (N * 16) / 256;       // 6250 exact
    const int gridG  = (N + 63) / 64;        // 1563

    // ---- CSR build ----
    hipMemsetAsync(degi, 0, (size_t)N * 4, stream);
    deg_count<<<gridE, 256, 0, stream>>>(row, degi, E);
    coef_kernel<<<1, 64, 0, stream>>>(ap, coef);
    scan_a<<<gridN, 256, 0, stream>>>(degi, rowStart, bs, N);
    scan_b<<<1, 512, 0, stream>>>(bs, gridN);
    scan_c<<<gridN, 256, 0, stream>>>(rowStart, bs, N, E);
    dis_kernel<<<gridN, 256, 0, stream>>>(degi, dis, N);
    hipMemsetAsync(degi, 0, (size_t)N * 4, stream);        // reuse as cursor
    scatter_kernel<<<gridE, 256, 0, stream>>>(row, col, ew, dis, rowStart, degi, ev, E);

    // ---- L=1: A = c0*x + c1*(adj@x) ----
    spmm_fused<0><<<gridSp, 256, 0, stream>>>(rowStart, ev, (const float4*)x,
                                              (const float4*)x, (const float4*)x,
                                              (float4*)A, coef, 0, N);
    // ---- L=2: B = c0*(adj@A) - c1*A - c2*x ----
    spmm_fused<1><<<gridSp, 256, 0, stream>>>(rowStart, ev, (const float4*)A,
                                              (const float4*)A, (const float4*)x,
                                              (float4*)B, coef, 2, N);
    // ---- L=3: C = c0*(adj@B) - c1*B - c2*A ----
    spmm_fused<1><<<gridSp, 256, 0, stream>>>(rowStart, ev, (const float4*)B,
                                              (const float4*)B, (const float4*)A,
                                              (float4*)C, coef, 5, N);

    // ---- out = [x | A | B | C] @ W + b ----
    final_gemm<<<gridG, 256, 0, stream>>>(x, A, B, C, lw, lb, out);
}

// Round 6
// 392.728 us; speedup vs baseline: 7.0598x; 1.1120x over previous
//
#include <hip/hip_runtime.h>
#include <hip/hip_bf16.h>
#include <math.h>

#define NN 100000
#define EE 1250000
#define DD 64

// bf16 helpers (RNE)
__device__ __forceinline__ unsigned short f2b(float f) {
    unsigned u = __float_as_uint(f);
    u += 0x7fffu + ((u >> 16) & 1u);
    return (unsigned short)(u >> 16);
}
__device__ __forceinline__ float b2f(unsigned short h) {
    return __uint_as_float(((unsigned)h) << 16);
}

// ---------------- degree count (int atomics) ----------------
__global__ __launch_bounds__(256) void deg_count(const int* __restrict__ row,
                                                 int* __restrict__ degi, int E) {
    int e = blockIdx.x * 256 + threadIdx.x;
    if (e >= E) return;
    atomicAdd(&degi[row[e]], 1);
}

// ---------------- scan step A: per-block exclusive scan + block sums ----------
__global__ __launch_bounds__(256) void scan_a(const int* __restrict__ degi,
                                              int* __restrict__ rowStart,
                                              int* __restrict__ bs, int N) {
    __shared__ int s[256];
    int tid = threadIdx.x;
    int i = blockIdx.x * 256 + tid;
    int v = (i < N) ? degi[i] : 0;
    s[tid] = v;
    __syncthreads();
    for (int off = 1; off < 256; off <<= 1) {
        int t = (tid >= off) ? s[tid - off] : 0;
        __syncthreads();
        s[tid] += t;
        __syncthreads();
    }
    if (i < N) rowStart[i] = s[tid] - v;   // exclusive
    if (tid == 255) bs[blockIdx.x] = s[255];
}

// ---------------- scan step B: exclusive scan of block sums (1 block) --------
__global__ __launch_bounds__(512) void scan_b(int* __restrict__ bs, int nb) {
    __shared__ int s[512];
    int tid = threadIdx.x;
    int v = (tid < nb) ? bs[tid] : 0;
    s[tid] = v;
    __syncthreads();
    for (int off = 1; off < 512; off <<= 1) {
        int t = (tid >= off) ? s[tid - off] : 0;
        __syncthreads();
        s[tid] += t;
        __syncthreads();
    }
    if (tid < nb) bs[tid] = s[tid] - v;    // exclusive
}

// ---------------- scan step C: add block offsets, set rowStart[N]=E ----------
__global__ __launch_bounds__(256) void scan_c(int* __restrict__ rowStart,
                                              const int* __restrict__ bs,
                                              int N, int E) {
    int i = blockIdx.x * 256 + threadIdx.x;
    if (i < N) rowStart[i] += bs[blockIdx.x];
    if (i == 0) rowStart[N] = E;
}

// ---------------- dis = deg^-0.5 (deg==0 -> 1) ----------------
__global__ __launch_bounds__(256) void dis_kernel(const int* __restrict__ degi,
                                                  float* __restrict__ dis, int N) {
    int i = blockIdx.x * 256 + threadIdx.x;
    if (i >= N) return;
    int d = degi[i];
    float df = (d == 0) ? 1.0f : (float)d;
    dis[i] = 1.0f / sqrtf(df);
}

// ---------------- scatter edges into CSR order, pack (val, col) --------------
// nt store: ev lines are never re-read by this kernel; avoid L2 dirty thrash
// (R5: WRITE_SIZE 81 MB for a 10 MB buffer = 8-XCD false sharing).
__global__ __launch_bounds__(256) void scatter_kernel(const int* __restrict__ row,
                                                      const int* __restrict__ col,
                                                      const float* __restrict__ w,
                                                      const float* __restrict__ dis,
                                                      const int* __restrict__ rowStart,
                                                      int* __restrict__ cursor,
                                                      float2* __restrict__ ev, int E) {
    int e = blockIdx.x * 256 + threadIdx.x;
    if (e >= E) return;
    int r = row[e], c = col[e];
    int pos = rowStart[r] + atomicAdd(&cursor[r], 1);
    float v = dis[r] * w[e] * dis[c];
    union { float2 f; long long l; } u;
    u.f = make_float2(v, __int_as_float(c));
    __builtin_nontemporal_store(u.l, (long long*)&ev[pos]);
}

// ---------------- scalar coefficients ----------------
// layout: [0]=al0*coef1, [1]=al0*coef2, [2..4]=L2 {tmp1_2,tmp2_2,tmp3}, [5..7]=L3
__global__ void coef_kernel(const float* __restrict__ ap, float* __restrict__ coef) {
    if (threadIdx.x != 0 || blockIdx.x != 0) return;
    const float a = 1.0f, b = 1.0f, l = -1.0f, r = 1.0f;
    float als[3];
    als[0] = tanhf(ap[0]);
    als[1] = tanhf(ap[1]);
    als[2] = tanhf(ap[2]);
    float coef1 = (a - b) * 0.5f - (a + b + 2.0f) * 0.5f * ((l + r) / (r - l));
    float coef2 = (a + b + 2.0f) / (r - l);
    coef[0] = als[0] * coef1;
    coef[1] = als[0] * coef2;
    for (int L = 2; L <= 3; ++L) {
        float Lf = (float)L;
        float coef_l     = 2.0f * Lf * (Lf + a + b) * (2.0f * Lf - 2.0f + a + b);
        float coef_lm1_1 = (2.0f * Lf + a + b - 1.0f) * (2.0f * Lf + a + b) * (2.0f * Lf + a + b - 2.0f);
        float coef_lm1_2 = (2.0f * Lf + a + b - 1.0f) * (a * a - b * b);
        float coef_lm2   = 2.0f * (Lf - 1.0f + a) * (Lf - 1.0f + b) * (2.0f * Lf + a + b);
        float tmp1   = als[L - 1] * (coef_lm1_1 / coef_l);
        float tmp2   = als[L - 1] * (coef_lm1_2 / coef_l);
        float tmp3   = als[L - 1] * als[L - 2] * (coef_lm2 / coef_l);
        float tmp1_2 = tmp1 * (2.0f / (r - l));
        float tmp2_2 = tmp1 * ((r + l) / (r - l)) + tmp2;
        int base = 2 + (L - 2) * 3;
        coef[base + 0] = tmp1_2;
        coef[base + 1] = tmp2_2;
        coef[base + 2] = tmp3;
    }
}

// ---------------- fp32 -> bf16 copy (vectorized) ----------------
__global__ __launch_bounds__(256) void tobf16(const float4* __restrict__ in,
                                              ushort4* __restrict__ outb, int n4) {
    int i = blockIdx.x * 256 + threadIdx.x;
    if (i >= n4) return;
    float4 v = in[i];
    ushort4 o;
    o.x = f2b(v.x); o.y = f2b(v.y); o.z = f2b(v.z); o.w = f2b(v.w);
    outb[i] = o;
}

// ---------------- fused CSR SpMM + combine, bf16 gather ----------------
// 16 lanes per row (one ushort4 = 4 bf16 each). Accumulate fp32.
// MODE 0: out = c0*xm1 + c1*Ax ;  MODE 1: out = c0*Ax - c1*xm1 - c2*xm2
// WB: also emit bf16 copy of the output (gather operand for the next level).
template <int MODE, int WB>
__global__ __launch_bounds__(256) void spmm_fused(const int* __restrict__ rowStart,
                                                  const float2* __restrict__ ev,
                                                  const ushort4* __restrict__ hb,
                                                  const float4* __restrict__ xm1,
                                                  const float4* __restrict__ xm2,
                                                  float4* __restrict__ outp,
                                                  ushort4* __restrict__ outb,
                                                  const float* __restrict__ coef,
                                                  int cbase, int N) {
    int t = blockIdx.x * 256 + threadIdx.x;
    int r = t >> 4;
    if (r >= N) return;
    int q = t & 15;
    int s0 = rowStart[r];
    int s1 = rowStart[r + 1];
    float4 acc = make_float4(0.f, 0.f, 0.f, 0.f);
    int j = s0;
    // unroll x2: two gathers in flight
    for (; j + 1 < s1; j += 2) {
        float2 e0 = ev[j];
        float2 e1 = ev[j + 1];
        int c0i = __float_as_int(e0.y);
        int c1i = __float_as_int(e1.y);
        ushort4 h0 = hb[(size_t)c0i * 16 + q];
        ushort4 h1 = hb[(size_t)c1i * 16 + q];
        acc.x += e0.x * b2f(h0.x) + e1.x * b2f(h1.x);
        acc.y += e0.x * b2f(h0.y) + e1.x * b2f(h1.y);
        acc.z += e0.x * b2f(h0.z) + e1.x * b2f(h1.z);
        acc.w += e0.x * b2f(h0.w) + e1.x * b2f(h1.w);
    }
    if (j < s1) {
        float2 e0 = ev[j];
        int c0i = __float_as_int(e0.y);
        ushort4 h0 = hb[(size_t)c0i * 16 + q];
        acc.x += e0.x * b2f(h0.x);
        acc.y += e0.x * b2f(h0.y);
        acc.z += e0.x * b2f(h0.z);
        acc.w += e0.x * b2f(h0.w);
    }
    size_t oi = (size_t)r * 16 + q;
    float4 o;
    if (MODE == 0) {
        float c0 = coef[cbase], c1 = coef[cbase + 1];
        float4 m1 = xm1[oi];
        o.x = c0 * m1.x + c1 * acc.x;
        o.y = c0 * m1.y + c1 * acc.y;
        o.z = c0 * m1.z + c1 * acc.z;
        o.w = c0 * m1.w + c1 * acc.w;
    } else {
        float c0 = coef[cbase], c1 = coef[cbase + 1], c2 = coef[cbase + 2];
        float4 m1 = xm1[oi];
        float4 m2 = xm2[oi];
        o.x = c0 * acc.x - c1 * m1.x - c2 * m2.x;
        o.y = c0 * acc.y - c1 * m1.y - c2 * m2.y;
        o.z = c0 * acc.z - c1 * m1.z - c2 * m2.z;
        o.w = c0 * acc.w - c1 * m1.w - c2 * m2.w;
    }
    outp[oi] = o;
    if (WB) {
        ushort4 ob;
        ob.x = f2b(o.x); ob.y = f2b(o.y); ob.z = f2b(o.z); ob.w = f2b(o.w);
        outb[oi] = ob;
    }
}

// ---------------- final fused GEMM: out = [x|A|B|C] @ W + bias ----------------
// Register-tiled: block 256 threads = 64x64 output tile, 4x4 per thread.
// Thread (tx,ty) owns rows {ty, ty+16, ty+32, ty+48} (strided -> 2-way LDS
// aliasing = free) and cols tx*4..+3. LDX=68 keeps rows 16B-aligned.
// seg loop `#pragma unroll 1` (R3: full unroll -> 256 VGPR spill);
// NO min-waves clamp (R4: forced 64 VGPR -> spill). All fp32.
#define LDX 68
__global__ __launch_bounds__(256) void final_gemm(const float* __restrict__ x0,
                                                  const float* __restrict__ x1,
                                                  const float* __restrict__ x2,
                                                  const float* __restrict__ x3,
                                                  const float* __restrict__ W,
                                                  const float* __restrict__ bias,
                                                  float* __restrict__ out) {
    __shared__ float Xs[64 * LDX];
    __shared__ float Ws[64 * 64];
    const int tid = threadIdx.x;
    const int tx = tid & 15;
    const int ty = tid >> 4;
    const int n0 = (int)blockIdx.x * 64;

    float acc[4][4];
    {
        float4 bv = ((const float4*)bias)[tx];
        #pragma unroll
        for (int i = 0; i < 4; ++i) {
            acc[i][0] = bv.x; acc[i][1] = bv.y; acc[i][2] = bv.z; acc[i][3] = bv.w;
        }
    }

    #pragma unroll 1
    for (int seg = 0; seg < 4; ++seg) {
        const float* p = (seg == 0) ? x0 : (seg == 1) ? x1 : (seg == 2) ? x2 : x3;
        {
            const float4* Wg = (const float4*)(W + seg * 64 * 64);
            float4* Ws4 = (float4*)Ws;
            #pragma unroll
            for (int j = 0; j < 4; ++j) Ws4[tid + 256 * j] = Wg[tid + 256 * j];
        }
        {
            const float4* Xg = (const float4*)p;
            #pragma unroll
            for (int j = 0; j < 4; ++j) {
                int idx = tid + 256 * j;
                int r = idx >> 4, c4 = idx & 15;
                int gr = n0 + r;
                float4 v = (gr < NN) ? Xg[(size_t)gr * 16 + c4]
                                     : make_float4(0.f, 0.f, 0.f, 0.f);
                *((float4*)&Xs[r * LDX + c4 * 4]) = v;
            }
        }
        __syncthreads();
        #pragma unroll 2
        for (int k = 0; k < 64; k += 4) {
            float4 xf[4], wf[4];
            #pragma unroll
            for (int i = 0; i < 4; ++i)
                xf[i] = *((const float4*)&Xs[(ty + 16 * i) * LDX + k]);
            #pragma unroll
            for (int u = 0; u < 4; ++u)
                wf[u] = *((const float4*)&Ws[(k + u) * 64 + tx * 4]);
            #pragma unroll
            for (int i = 0; i < 4; ++i) {
                acc[i][0] += xf[i].x * wf[0].x + xf[i].y * wf[1].x
                           + xf[i].z * wf[2].x + xf[i].w * wf[3].x;
                acc[i][1] += xf[i].x * wf[0].y + xf[i].y * wf[1].y
                           + xf[i].z * wf[2].y + xf[i].w * wf[3].y;
                acc[i][2] += xf[i].x * wf[0].z + xf[i].y * wf[1].z
                           + xf[i].z * wf[2].z + xf[i].w * wf[3].z;
                acc[i][3] += xf[i].x * wf[0].w + xf[i].y * wf[1].w
                           + xf[i].z * wf[2].w + xf[i].w * wf[3].w;
            }
        }
        __syncthreads();
    }
    #pragma unroll
    for (int i = 0; i < 4; ++i) {
        int gr = n0 + ty + 16 * i;
        if (gr < NN) {
            float4 o = make_float4(acc[i][0], acc[i][1], acc[i][2], acc[i][3]);
            ((float4*)out)[(size_t)gr * 16 + tx] = o;
        }
    }
}

extern "C" void kernel_launch(void* const* d_in, const int* in_sizes, int n_in,
                              void* d_out, int out_size, void* d_ws, size_t ws_size,
                              hipStream_t stream) {
    const float* x  = (const float*)d_in[0];
    const int*   ei = (const int*)d_in[1];
    const float* ew = (const float*)d_in[2];
    const float* ap = (const float*)d_in[3];
    const float* lw = (const float*)d_in[4];
    const float* lb = (const float*)d_in[5];
    float* out = (float*)d_out;

    const int N = NN, E = EE;
    const int ND = N * DD;

    const int* row = ei;
    const int* col = ei + E;

    // workspace layout (big 16B-aligned buffers first)
    char* ws = (char*)d_ws;
    float* A   = (float*)ws;                               // 25.6 MB
    float* B   = (float*)(ws + (size_t)ND * 4);            // 25.6 MB
    float* C   = (float*)(ws + (size_t)ND * 8);            // 25.6 MB
    float2* ev = (float2*)(ws + (size_t)ND * 12);          // 10 MB
    char* sm   = ws + (size_t)ND * 12 + (size_t)E * 8;
    float* coef     = (float*)sm;                          // 256 B
    float* dis      = (float*)(sm + 256);                  // N floats
    int*   degi     = (int*)(sm + 256 + (size_t)N * 4);    // N ints (also cursor)
    int*   rowStart = (int*)(sm + 256 + (size_t)N * 8);    // N+1 ints
    int*   bs       = (int*)(sm + 256 + (size_t)N * 12 + 64); // 512 ints

    // bf16 gather-operand overlays (no extra ws):
    //  xb lives in d_out during spmm1; Bb reuses d_out (xb dead) for spmm2->3;
    //  Ab overlays the C region (dead before spmm3 writes C);
    //  final_gemm overwrites d_out last.
    ushort4* xb = (ushort4*)d_out;
    ushort4* Bb = (ushort4*)d_out;
    ushort4* Ab = (ushort4*)C;

    const int gridE  = (E + 255) / 256;      // 4883
    const int gridN  = (N + 255) / 256;      // 391
    const int gridSp = (N * 16) / 256;       // 6250 exact
    const int gridCv = (ND / 4) / 256;       // 6250 exact
    const int gridG  = (N + 63) / 64;        // 1563

    // ---- CSR build ----
    hipMemsetAsync(degi, 0, (size_t)N * 4, stream);
    deg_count<<<gridE, 256, 0, stream>>>(row, degi, E);
    coef_kernel<<<1, 64, 0, stream>>>(ap, coef);
    scan_a<<<gridN, 256, 0, stream>>>(degi, rowStart, bs, N);
    scan_b<<<1, 512, 0, stream>>>(bs, gridN);
    scan_c<<<gridN, 256, 0, stream>>>(rowStart, bs, N, E);
    dis_kernel<<<gridN, 256, 0, stream>>>(degi, dis, N);
    hipMemsetAsync(degi, 0, (size_t)N * 4, stream);        // reuse as cursor
    scatter_kernel<<<gridE, 256, 0, stream>>>(row, col, ew, dis, rowStart, degi, ev, E);

    // ---- bf16 copy of x for the L=1 gather ----
    tobf16<<<gridCv, 256, 0, stream>>>((const float4*)x, xb, ND / 4);

    // ---- L=1: A = c0*x + c1*(adj@x); also emit Ab (bf16) ----
    spmm_fused<0, 1><<<gridSp, 256, 0, stream>>>(rowStart, ev, xb,
                                                 (const float4*)x, (const float4*)x,
                                                 (float4*)A, Ab, coef, 0, N);
    // ---- L=2: B = c0*(adj@A) - c1*A - c2*x; also emit Bb (bf16, over xb) ----
    spmm_fused<1, 1><<<gridSp, 256, 0, stream>>>(rowStart, ev, Ab,
                                                 (const float4*)A, (const float4*)x,
                                                 (float4*)B, Bb, coef, 2, N);
    // ---- L=3: C = c0*(adj@B) - c1*B - c2*A (C overwrites dead Ab region) ----
    spmm_fused<1, 0><<<gridSp, 256, 0, stream>>>(rowStart, ev, Bb,
                                                 (const float4*)B, (const float4*)A,
                                                 (float4*)C, (ushort4*)nullptr, coef, 5, N);

    // ---- out = [x | A | B | C] @ W + b ----
    final_gemm<<<gridG, 256, 0, stream>>>(x, A, B, C, lw, lb, out);
}

// Round 7
// 377.116 us; speedup vs baseline: 7.3521x; 1.0414x over previous
//
#include <hip/hip_runtime.h>
#include <hip/hip_bf16.h>
#include <math.h>

#define NN 100000
#define EE 1250000
#define DD 64

typedef __attribute__((ext_vector_type(8))) short short8;
typedef __attribute__((ext_vector_type(4))) float f32x4;

// bf16 helpers (RNE)
__device__ __forceinline__ unsigned short f2b(float f) {
    unsigned u = __float_as_uint(f);
    u += 0x7fffu + ((u >> 16) & 1u);
    return (unsigned short)(u >> 16);
}
__device__ __forceinline__ float b2f(unsigned short h) {
    return __uint_as_float(((unsigned)h) << 16);
}

// ---------------- degree count (int atomics) ----------------
__global__ __launch_bounds__(256) void deg_count(const int* __restrict__ row,
                                                 int* __restrict__ degi, int E) {
    int e = blockIdx.x * 256 + threadIdx.x;
    if (e >= E) return;
    atomicAdd(&degi[row[e]], 1);
}

// ---------------- scan step A ----------------
__global__ __launch_bounds__(256) void scan_a(const int* __restrict__ degi,
                                              int* __restrict__ rowStart,
                                              int* __restrict__ bs, int N) {
    __shared__ int s[256];
    int tid = threadIdx.x;
    int i = blockIdx.x * 256 + tid;
    int v = (i < N) ? degi[i] : 0;
    s[tid] = v;
    __syncthreads();
    for (int off = 1; off < 256; off <<= 1) {
        int t = (tid >= off) ? s[tid - off] : 0;
        __syncthreads();
        s[tid] += t;
        __syncthreads();
    }
    if (i < N) rowStart[i] = s[tid] - v;   // exclusive
    if (tid == 255) bs[blockIdx.x] = s[255];
}

// ---------------- scan step B (1 block) ----------------
__global__ __launch_bounds__(512) void scan_b(int* __restrict__ bs, int nb) {
    __shared__ int s[512];
    int tid = threadIdx.x;
    int v = (tid < nb) ? bs[tid] : 0;
    s[tid] = v;
    __syncthreads();
    for (int off = 1; off < 512; off <<= 1) {
        int t = (tid >= off) ? s[tid - off] : 0;
        __syncthreads();
        s[tid] += t;
        __syncthreads();
    }
    if (tid < nb) bs[tid] = s[tid] - v;    // exclusive
}

// ---------------- scan step C ----------------
__global__ __launch_bounds__(256) void scan_c(int* __restrict__ rowStart,
                                              const int* __restrict__ bs,
                                              int N, int E) {
    int i = blockIdx.x * 256 + threadIdx.x;
    if (i < N) rowStart[i] += bs[blockIdx.x];
    if (i == 0) rowStart[N] = E;
}

// ---------------- dis = deg^-0.5 (deg==0 -> 1) ----------------
__global__ __launch_bounds__(256) void dis_kernel(const int* __restrict__ degi,
                                                  float* __restrict__ dis, int N) {
    int i = blockIdx.x * 256 + threadIdx.x;
    if (i >= N) return;
    int d = degi[i];
    float df = (d == 0) ? 1.0f : (float)d;
    dis[i] = 1.0f / sqrtf(df);
}

// ---------------- scatter edges into CSR order ----------------
__global__ __launch_bounds__(256) void scatter_kernel(const int* __restrict__ row,
                                                      const int* __restrict__ col,
                                                      const float* __restrict__ w,
                                                      const float* __restrict__ dis,
                                                      const int* __restrict__ rowStart,
                                                      int* __restrict__ cursor,
                                                      float2* __restrict__ ev, int E) {
    int e = blockIdx.x * 256 + threadIdx.x;
    if (e >= E) return;
    int r = row[e], c = col[e];
    int pos = rowStart[r] + atomicAdd(&cursor[r], 1);
    float v = dis[r] * w[e] * dis[c];
    union { float2 f; long long l; } u;
    u.f = make_float2(v, __int_as_float(c));
    __builtin_nontemporal_store(u.l, (long long*)&ev[pos]);
}

// ---------------- scalar coefficients ----------------
__global__ void coef_kernel(const float* __restrict__ ap, float* __restrict__ coef) {
    if (threadIdx.x != 0 || blockIdx.x != 0) return;
    const float a = 1.0f, b = 1.0f, l = -1.0f, r = 1.0f;
    float als[3];
    als[0] = tanhf(ap[0]);
    als[1] = tanhf(ap[1]);
    als[2] = tanhf(ap[2]);
    float coef1 = (a - b) * 0.5f - (a + b + 2.0f) * 0.5f * ((l + r) / (r - l));
    float coef2 = (a + b + 2.0f) / (r - l);
    coef[0] = als[0] * coef1;
    coef[1] = als[0] * coef2;
    for (int L = 2; L <= 3; ++L) {
        float Lf = (float)L;
        float coef_l     = 2.0f * Lf * (Lf + a + b) * (2.0f * Lf - 2.0f + a + b);
        float coef_lm1_1 = (2.0f * Lf + a + b - 1.0f) * (2.0f * Lf + a + b) * (2.0f * Lf + a + b - 2.0f);
        float coef_lm1_2 = (2.0f * Lf + a + b - 1.0f) * (a * a - b * b);
        float coef_lm2   = 2.0f * (Lf - 1.0f + a) * (Lf - 1.0f + b) * (2.0f * Lf + a + b);
        float tmp1   = als[L - 1] * (coef_lm1_1 / coef_l);
        float tmp2   = als[L - 1] * (coef_lm1_2 / coef_l);
        float tmp3   = als[L - 1] * als[L - 2] * (coef_lm2 / coef_l);
        float tmp1_2 = tmp1 * (2.0f / (r - l));
        float tmp2_2 = tmp1 * ((r + l) / (r - l)) + tmp2;
        int base = 2 + (L - 2) * 3;
        coef[base + 0] = tmp1_2;
        coef[base + 1] = tmp2_2;
        coef[base + 2] = tmp3;
    }
}

// ---------------- fp32 -> bf16 copy ----------------
__global__ __launch_bounds__(256) void tobf16(const float4* __restrict__ in,
                                              ushort4* __restrict__ outb, int n4) {
    int i = blockIdx.x * 256 + threadIdx.x;
    if (i >= n4) return;
    float4 v = in[i];
    ushort4 o;
    o.x = f2b(v.x); o.y = f2b(v.y); o.z = f2b(v.z); o.w = f2b(v.w);
    outb[i] = o;
}

// ---------------- W transpose to bf16 [n][k] (B^T layout for MFMA) ----------
__global__ __launch_bounds__(256) void wt_kernel(const float* __restrict__ W,
                                                 unsigned short* __restrict__ Wt) {
    int idx = blockIdx.x * 256 + threadIdx.x;   // 0..16383
    int n = idx >> 8, k = idx & 255;
    Wt[idx] = f2b(W[k * 64 + n]);
}

// ---------------- fused CSR SpMM + combine, bf16 gather ----------------
// 16 lanes per row. MODE 0: out = c0*xm1 + c1*Ax; MODE 1: out = c0*Ax - c1*xm1 - c2*xm2
// WF: write fp32 output; WB: write bf16 output. Edge loop unrolled x4 (MLP).
template <int MODE, int WB, int WF>
__global__ __launch_bounds__(256) void spmm_fused(const int* __restrict__ rowStart,
                                                  const float2* __restrict__ ev,
                                                  const ushort4* __restrict__ hb,
                                                  const float4* __restrict__ xm1,
                                                  const float4* __restrict__ xm2,
                                                  float4* __restrict__ outp,
                                                  ushort4* __restrict__ outb,
                                                  const float* __restrict__ coef,
                                                  int cbase, int N) {
    int t = blockIdx.x * 256 + threadIdx.x;
    int r = t >> 4;
    if (r >= N) return;
    int q = t & 15;
    int s0 = rowStart[r];
    int s1 = rowStart[r + 1];
    float4 acc = make_float4(0.f, 0.f, 0.f, 0.f);
    int j = s0;
    for (; j + 3 < s1; j += 4) {
        float2 e0 = ev[j];
        float2 e1 = ev[j + 1];
        float2 e2 = ev[j + 2];
        float2 e3 = ev[j + 3];
        ushort4 h0 = hb[(size_t)__float_as_int(e0.y) * 16 + q];
        ushort4 h1 = hb[(size_t)__float_as_int(e1.y) * 16 + q];
        ushort4 h2 = hb[(size_t)__float_as_int(e2.y) * 16 + q];
        ushort4 h3 = hb[(size_t)__float_as_int(e3.y) * 16 + q];
        acc.x += e0.x * b2f(h0.x) + e1.x * b2f(h1.x) + e2.x * b2f(h2.x) + e3.x * b2f(h3.x);
        acc.y += e0.x * b2f(h0.y) + e1.x * b2f(h1.y) + e2.x * b2f(h2.y) + e3.x * b2f(h3.y);
        acc.z += e0.x * b2f(h0.z) + e1.x * b2f(h1.z) + e2.x * b2f(h2.z) + e3.x * b2f(h3.z);
        acc.w += e0.x * b2f(h0.w) + e1.x * b2f(h1.w) + e2.x * b2f(h2.w) + e3.x * b2f(h3.w);
    }
    for (; j < s1; ++j) {
        float2 e0 = ev[j];
        ushort4 h0 = hb[(size_t)__float_as_int(e0.y) * 16 + q];
        acc.x += e0.x * b2f(h0.x);
        acc.y += e0.x * b2f(h0.y);
        acc.z += e0.x * b2f(h0.z);
        acc.w += e0.x * b2f(h0.w);
    }
    size_t oi = (size_t)r * 16 + q;
    float4 o;
    if (MODE == 0) {
        float c0 = coef[cbase], c1 = coef[cbase + 1];
        float4 m1 = xm1[oi];
        o.x = c0 * m1.x + c1 * acc.x;
        o.y = c0 * m1.y + c1 * acc.y;
        o.z = c0 * m1.z + c1 * acc.z;
        o.w = c0 * m1.w + c1 * acc.w;
    } else {
        float c0 = coef[cbase], c1 = coef[cbase + 1], c2 = coef[cbase + 2];
        float4 m1 = xm1[oi];
        float4 m2 = xm2[oi];
        o.x = c0 * acc.x - c1 * m1.x - c2 * m2.x;
        o.y = c0 * acc.y - c1 * m1.y - c2 * m2.y;
        o.z = c0 * acc.z - c1 * m1.z - c2 * m2.z;
        o.w = c0 * acc.w - c1 * m1.w - c2 * m2.w;
    }
    if (WF) outp[oi] = o;
    if (WB) {
        ushort4 ob;
        ob.x = f2b(o.x); ob.y = f2b(o.y); ob.z = f2b(o.z); ob.w = f2b(o.w);
        outb[oi] = ob;
    }
}

// ---------------- final GEMM via MFMA: out = [x|A|B|C] @ W + bias -----------
// Block = 256 thr (4 waves) = 64 node rows. X staged as bf16 in LDS
// (stride 264 bf16 = 528 B: A-frag b128 reads land 2 lanes/bank-quad = free).
// W read from the 32 KB pre-transposed bf16 Wt[n][k] (B^T layout) straight
// from global (L1-resident). 8 k-steps x 4 n-tiles of mfma_f32_16x16x32_bf16.
// Layouts (verified, guide §3): A[m=lane&15][k=quad*8+j];
// D: col=lane&15, row=quad*4+reg.
#define XLD 264
__global__ __launch_bounds__(256) void final_gemm_mfma(
        const float4* __restrict__ x0,
        const float4* __restrict__ x1,
        const float4* __restrict__ x2,
        const ushort4* __restrict__ x3b,
        const unsigned short* __restrict__ Wt,
        const float* __restrict__ bias,
        float* __restrict__ out) {
    __shared__ unsigned short Xb[64 * XLD];
    const int tid = threadIdx.x;
    const int lane = tid & 63;
    const int w = tid >> 6;
    const int m = lane & 15;
    const int quad = lane >> 4;
    const int n0 = (int)blockIdx.x * 64;

    // stage 64 rows x K=256 as bf16 (segs 0..2 from fp32, seg 3 from bf16 Cb)
    #pragma unroll 1
    for (int seg = 0; seg < 4; ++seg) {
        #pragma unroll
        for (int j = 0; j < 4; ++j) {
            int idx = tid + 256 * j;          // 0..1023
            int r = idx >> 4, c4 = idx & 15;
            int gr = n0 + r;
            ushort4 hv;
            if (seg == 3) {
                hv = (gr < NN) ? x3b[(size_t)gr * 16 + c4] : make_ushort4(0, 0, 0, 0);
            } else {
                const float4* p = (seg == 0) ? x0 : (seg == 1) ? x1 : x2;
                float4 v = (gr < NN) ? p[(size_t)gr * 16 + c4]
                                     : make_float4(0.f, 0.f, 0.f, 0.f);
                hv.x = f2b(v.x); hv.y = f2b(v.y); hv.z = f2b(v.z); hv.w = f2b(v.w);
            }
            *(ushort4*)&Xb[r * XLD + seg * 64 + c4 * 4] = hv;
        }
    }
    __syncthreads();

    f32x4 acc[4];
    #pragma unroll
    for (int nt = 0; nt < 4; ++nt) acc[nt] = (f32x4){0.f, 0.f, 0.f, 0.f};

    #pragma unroll 1
    for (int ks = 0; ks < 8; ++ks) {
        short8 af = *(const short8*)&Xb[(16 * w + m) * XLD + ks * 32 + quad * 8];
        #pragma unroll
        for (int nt = 0; nt < 4; ++nt) {
            short8 bf = *(const short8*)&Wt[(nt * 16 + m) * 256 + ks * 32 + quad * 8];
            acc[nt] = __builtin_amdgcn_mfma_f32_16x16x32_bf16(af, bf, acc[nt], 0, 0, 0);
        }
    }

    // epilogue: D row = quad*4+reg (node), col = nt*16 + m (feature)
    #pragma unroll
    for (int nt = 0; nt < 4; ++nt) {
        float bv = bias[nt * 16 + m];
        #pragma unroll
        for (int rg = 0; rg < 4; ++rg) {
            int node = n0 + 16 * w + quad * 4 + rg;
            if (node < NN) out[(size_t)node * 64 + nt * 16 + m] = acc[nt][rg] + bv;
        }
    }
}

extern "C" void kernel_launch(void* const* d_in, const int* in_sizes, int n_in,
                              void* d_out, int out_size, void* d_ws, size_t ws_size,
                              hipStream_t stream) {
    const float* x  = (const float*)d_in[0];
    const int*   ei = (const int*)d_in[1];
    const float* ew = (const float*)d_in[2];
    const float* ap = (const float*)d_in[3];
    const float* lw = (const float*)d_in[4];
    const float* lb = (const float*)d_in[5];
    float* out = (float*)d_out;

    const int N = NN, E = EE;
    const int ND = N * DD;

    const int* row = ei;
    const int* col = ei + E;

    // workspace layout (16B-aligned):
    //  A fp32 | B fp32 | pool(Ab,Cb bf16) | ev | small
    char* ws = (char*)d_ws;
    float* A    = (float*)ws;                              // 25.6 MB
    float* B    = (float*)(ws + (size_t)ND * 4);           // 25.6 MB
    char*  pool = ws + (size_t)ND * 8;                     // 25.6 MB
    ushort4* Ab = (ushort4*)pool;                          // 12.8 MB
    ushort4* Cb = (ushort4*)(pool + (size_t)ND * 2);       // 12.8 MB
    float2* ev  = (float2*)(ws + (size_t)ND * 12);         // 10 MB
    char* sm    = ws + (size_t)ND * 12 + (size_t)E * 8;
    float* coef     = (float*)sm;                          // 256 B
    float* dis      = (float*)(sm + 256);                  // N floats
    int*   degi     = (int*)(sm + 256 + (size_t)N * 4);    // N ints (also cursor)
    int*   rowStart = (int*)(sm + 256 + (size_t)N * 8);    // N+1 ints
    int*   bs       = (int*)(sm + 256 + (size_t)N * 12 + 64);       // 512 ints
    unsigned short* Wt = (unsigned short*)(sm + 256 + (size_t)N * 12 + 64 + 4096); // 32 KB

    // bf16 overlays in d_out (both dead before final_gemm_mfma writes d_out):
    ushort4* xb = (ushort4*)d_out;                         // spmm1 gather src
    ushort4* Bb = (ushort4*)((char*)d_out + (size_t)ND * 2); // spmm3 gather src

    const int gridE  = (E + 255) / 256;      // 4883
    const int gridN  = (N + 255) / 256;      // 391
    const int gridSp = (N * 16) / 256;       // 6250 exact
    const int gridCv = (ND / 4) / 256;       // 6250 exact
    const int gridG  = (N + 63) / 64;        // 1563

    // ---- CSR build ----
    hipMemsetAsync(degi, 0, (size_t)N * 4, stream);
    deg_count<<<gridE, 256, 0, stream>>>(row, degi, E);
    coef_kernel<<<1, 64, 0, stream>>>(ap, coef);
    wt_kernel<<<64, 256, 0, stream>>>(lw, Wt);
    scan_a<<<gridN, 256, 0, stream>>>(degi, rowStart, bs, N);
    scan_b<<<1, 512, 0, stream>>>(bs, gridN);
    scan_c<<<gridN, 256, 0, stream>>>(rowStart, bs, N, E);
    dis_kernel<<<gridN, 256, 0, stream>>>(degi, dis, N);
    hipMemsetAsync(degi, 0, (size_t)N * 4, stream);        // reuse as cursor
    scatter_kernel<<<gridE, 256, 0, stream>>>(row, col, ew, dis, rowStart, degi, ev, E);

    // ---- bf16 copy of x for the L=1 gather ----
    tobf16<<<gridCv, 256, 0, stream>>>((const float4*)x, xb, ND / 4);

    // ---- L=1: A = c0*x + c1*(adj@x); emit Ab ----
    spmm_fused<0, 1, 1><<<gridSp, 256, 0, stream>>>(rowStart, ev, xb,
                                                    (const float4*)x, (const float4*)x,
                                                    (float4*)A, Ab, coef, 0, N);
    // ---- L=2: B = c0*(adj@A) - c1*A - c2*x; emit Bb ----
    spmm_fused<1, 1, 1><<<gridSp, 256, 0, stream>>>(rowStart, ev, Ab,
                                                    (const float4*)A, (const float4*)x,
                                                    (float4*)B, Bb, coef, 2, N);
    // ---- L=3: Cb(bf16 only) = c0*(adj@B) - c1*B - c2*A ----
    spmm_fused<1, 1, 0><<<gridSp, 256, 0, stream>>>(rowStart, ev, Bb,
                                                    (const float4*)B, (const float4*)A,
                                                    (float4*)nullptr, Cb, coef, 5, N);

    // ---- out = [x | A | B | C] @ W + b (MFMA) ----
    final_gemm_mfma<<<gridG, 256, 0, stream>>>((const float4*)x, (const float4*)A,
                                               (const float4*)B, Cb, Wt, lb, out);
}

// Round 8
// 371.740 us; speedup vs baseline: 7.4584x; 1.0145x over previous
//
#include <hip/hip_runtime.h>
#include <hip/hip_bf16.h>
#include <math.h>

#define NN 100000
#define EE 1250000
#define DD 64

typedef __attribute__((ext_vector_type(8))) short short8;
typedef __attribute__((ext_vector_type(4))) float f32x4;

// bf16 helpers (RNE)
__device__ __forceinline__ unsigned short f2b(float f) {
    unsigned u = __float_as_uint(f);
    u += 0x7fffu + ((u >> 16) & 1u);
    return (unsigned short)(u >> 16);
}
__device__ __forceinline__ float b2f(unsigned short h) {
    return __uint_as_float(((unsigned)h) << 16);
}

// ---------------- degree count (int atomics) ----------------
__global__ __launch_bounds__(256) void deg_count(const int* __restrict__ row,
                                                 int* __restrict__ degi, int E) {
    int e = blockIdx.x * 256 + threadIdx.x;
    if (e >= E) return;
    atomicAdd(&degi[row[e]], 1);
}

// ---------------- scan step A ----------------
__global__ __launch_bounds__(256) void scan_a(const int* __restrict__ degi,
                                              int* __restrict__ rowStart,
                                              int* __restrict__ bs, int N) {
    __shared__ int s[256];
    int tid = threadIdx.x;
    int i = blockIdx.x * 256 + tid;
    int v = (i < N) ? degi[i] : 0;
    s[tid] = v;
    __syncthreads();
    for (int off = 1; off < 256; off <<= 1) {
        int t = (tid >= off) ? s[tid - off] : 0;
        __syncthreads();
        s[tid] += t;
        __syncthreads();
    }
    if (i < N) rowStart[i] = s[tid] - v;   // exclusive
    if (tid == 255) bs[blockIdx.x] = s[255];
}

// ---------------- scan step B (1 block) ----------------
__global__ __launch_bounds__(512) void scan_b(int* __restrict__ bs, int nb) {
    __shared__ int s[512];
    int tid = threadIdx.x;
    int v = (tid < nb) ? bs[tid] : 0;
    s[tid] = v;
    __syncthreads();
    for (int off = 1; off < 512; off <<= 1) {
        int t = (tid >= off) ? s[tid - off] : 0;
        __syncthreads();
        s[tid] += t;
        __syncthreads();
    }
    if (tid < nb) bs[tid] = s[tid] - v;    // exclusive
}

// ---------------- scan step C ----------------
__global__ __launch_bounds__(256) void scan_c(int* __restrict__ rowStart,
                                              const int* __restrict__ bs,
                                              int N, int E) {
    int i = blockIdx.x * 256 + threadIdx.x;
    if (i < N) rowStart[i] += bs[blockIdx.x];
    if (i == 0) rowStart[N] = E;
}

// ---------------- dis = deg^-0.5 (deg==0 -> 1) ----------------
__global__ __launch_bounds__(256) void dis_kernel(const int* __restrict__ degi,
                                                  float* __restrict__ dis, int N) {
    int i = blockIdx.x * 256 + threadIdx.x;
    if (i >= N) return;
    int d = degi[i];
    float df = (d == 0) ? 1.0f : (float)d;
    dis[i] = 1.0f / sqrtf(df);
}

// ---------------- sliced scatter: CSR-order edges, XCD-local writes ---------
// ev is row-ordered, so rows [s*12500,(s+1)*12500) own one contiguous ~1.25MB
// slice. Block (chunk, slice=blockIdx&7) scans its edge chunk and writes only
// its slice. With the HW's round-robin block->XCD placement, each ev line is
// dirtied by one XCD -> ~1x writeback (R5-R7: random scatter gave 8x = 82 MB
// for a 10 MB buffer). Correct under ANY block->XCD mapping (perf-only
// heuristic). Plain stores (want L2 write-combining now that writes are local).
#define SCHUNK 2048
__global__ __launch_bounds__(256) void scatter_sliced(const int* __restrict__ row,
                                                      const int* __restrict__ col,
                                                      const float* __restrict__ w,
                                                      const float* __restrict__ dis,
                                                      const int* __restrict__ rowStart,
                                                      int* __restrict__ cursor,
                                                      float2* __restrict__ ev, int E) {
    const int slice = blockIdx.x & 7;
    const int base = (blockIdx.x >> 3) * SCHUNK;
    const int lo = slice * (NN / 8);
    const int hi = lo + (NN / 8);
    #pragma unroll
    for (int j = 0; j < SCHUNK; j += 256) {
        int e = base + j + threadIdx.x;
        if (e < E) {
            int r = row[e];
            if (r >= lo && r < hi) {
                int c = col[e];
                int pos = rowStart[r] + atomicAdd(&cursor[r], 1);
                float v = dis[r] * w[e] * dis[c];
                ev[pos] = make_float2(v, __int_as_float(c));
            }
        }
    }
}

// ---------------- scalar coefficients ----------------
__global__ void coef_kernel(const float* __restrict__ ap, float* __restrict__ coef) {
    if (threadIdx.x != 0 || blockIdx.x != 0) return;
    const float a = 1.0f, b = 1.0f, l = -1.0f, r = 1.0f;
    float als[3];
    als[0] = tanhf(ap[0]);
    als[1] = tanhf(ap[1]);
    als[2] = tanhf(ap[2]);
    float coef1 = (a - b) * 0.5f - (a + b + 2.0f) * 0.5f * ((l + r) / (r - l));
    float coef2 = (a + b + 2.0f) / (r - l);
    coef[0] = als[0] * coef1;
    coef[1] = als[0] * coef2;
    for (int L = 2; L <= 3; ++L) {
        float Lf = (float)L;
        float coef_l     = 2.0f * Lf * (Lf + a + b) * (2.0f * Lf - 2.0f + a + b);
        float coef_lm1_1 = (2.0f * Lf + a + b - 1.0f) * (2.0f * Lf + a + b) * (2.0f * Lf + a + b - 2.0f);
        float coef_lm1_2 = (2.0f * Lf + a + b - 1.0f) * (a * a - b * b);
        float coef_lm2   = 2.0f * (Lf - 1.0f + a) * (Lf - 1.0f + b) * (2.0f * Lf + a + b);
        float tmp1   = als[L - 1] * (coef_lm1_1 / coef_l);
        float tmp2   = als[L - 1] * (coef_lm1_2 / coef_l);
        float tmp3   = als[L - 1] * als[L - 2] * (coef_lm2 / coef_l);
        float tmp1_2 = tmp1 * (2.0f / (r - l));
        float tmp2_2 = tmp1 * ((r + l) / (r - l)) + tmp2;
        int base = 2 + (L - 2) * 3;
        coef[base + 0] = tmp1_2;
        coef[base + 1] = tmp2_2;
        coef[base + 2] = tmp3;
    }
}

// ---------------- fp32 -> bf16 copy ----------------
__global__ __launch_bounds__(256) void tobf16(const float4* __restrict__ in,
                                              ushort4* __restrict__ outb, int n4) {
    int i = blockIdx.x * 256 + threadIdx.x;
    if (i >= n4) return;
    float4 v = in[i];
    ushort4 o;
    o.x = f2b(v.x); o.y = f2b(v.y); o.z = f2b(v.z); o.w = f2b(v.w);
    outb[i] = o;
}

// ---------------- W transpose to bf16 [n][k] (B^T layout for MFMA) ----------
__global__ __launch_bounds__(256) void wt_kernel(const float* __restrict__ W,
                                                 unsigned short* __restrict__ Wt) {
    int idx = blockIdx.x * 256 + threadIdx.x;   // 0..16383
    int n = idx >> 8, k = idx & 255;
    Wt[idx] = f2b(W[k * 64 + n]);
}

// ---------------- fused CSR SpMM + combine, bf16 gather ----------------
// 16 lanes per row. MODE 0: out = c0*xm1 + c1*Ax; MODE 1: out = c0*Ax - c1*xm1 - c2*xm2
// WF: write fp32 output; WB: write bf16 output. Edge loop unrolled x4 (MLP).
template <int MODE, int WB, int WF>
__global__ __launch_bounds__(256) void spmm_fused(const int* __restrict__ rowStart,
                                                  const float2* __restrict__ ev,
                                                  const ushort4* __restrict__ hb,
                                                  const float4* __restrict__ xm1,
                                                  const float4* __restrict__ xm2,
                                                  float4* __restrict__ outp,
                                                  ushort4* __restrict__ outb,
                                                  const float* __restrict__ coef,
                                                  int cbase, int N) {
    int t = blockIdx.x * 256 + threadIdx.x;
    int r = t >> 4;
    if (r >= N) return;
    int q = t & 15;
    int s0 = rowStart[r];
    int s1 = rowStart[r + 1];
    float4 acc = make_float4(0.f, 0.f, 0.f, 0.f);
    int j = s0;
    for (; j + 3 < s1; j += 4) {
        float2 e0 = ev[j];
        float2 e1 = ev[j + 1];
        float2 e2 = ev[j + 2];
        float2 e3 = ev[j + 3];
        ushort4 h0 = hb[(size_t)__float_as_int(e0.y) * 16 + q];
        ushort4 h1 = hb[(size_t)__float_as_int(e1.y) * 16 + q];
        ushort4 h2 = hb[(size_t)__float_as_int(e2.y) * 16 + q];
        ushort4 h3 = hb[(size_t)__float_as_int(e3.y) * 16 + q];
        acc.x += e0.x * b2f(h0.x) + e1.x * b2f(h1.x) + e2.x * b2f(h2.x) + e3.x * b2f(h3.x);
        acc.y += e0.x * b2f(h0.y) + e1.x * b2f(h1.y) + e2.x * b2f(h2.y) + e3.x * b2f(h3.y);
        acc.z += e0.x * b2f(h0.z) + e1.x * b2f(h1.z) + e2.x * b2f(h2.z) + e3.x * b2f(h3.z);
        acc.w += e0.x * b2f(h0.w) + e1.x * b2f(h1.w) + e2.x * b2f(h2.w) + e3.x * b2f(h3.w);
    }
    for (; j < s1; ++j) {
        float2 e0 = ev[j];
        ushort4 h0 = hb[(size_t)__float_as_int(e0.y) * 16 + q];
        acc.x += e0.x * b2f(h0.x);
        acc.y += e0.x * b2f(h0.y);
        acc.z += e0.x * b2f(h0.z);
        acc.w += e0.x * b2f(h0.w);
    }
    size_t oi = (size_t)r * 16 + q;
    float4 o;
    if (MODE == 0) {
        float c0 = coef[cbase], c1 = coef[cbase + 1];
        float4 m1 = xm1[oi];
        o.x = c0 * m1.x + c1 * acc.x;
        o.y = c0 * m1.y + c1 * acc.y;
        o.z = c0 * m1.z + c1 * acc.z;
        o.w = c0 * m1.w + c1 * acc.w;
    } else {
        float c0 = coef[cbase], c1 = coef[cbase + 1], c2 = coef[cbase + 2];
        float4 m1 = xm1[oi];
        float4 m2 = xm2[oi];
        o.x = c0 * acc.x - c1 * m1.x - c2 * m2.x;
        o.y = c0 * acc.y - c1 * m1.y - c2 * m2.y;
        o.z = c0 * acc.z - c1 * m1.z - c2 * m2.z;
        o.w = c0 * acc.w - c1 * m1.w - c2 * m2.w;
    }
    if (WF) outp[oi] = o;
    if (WB) {
        ushort4 ob;
        ob.x = f2b(o.x); ob.y = f2b(o.y); ob.z = f2b(o.z); ob.w = f2b(o.w);
        outb[oi] = ob;
    }
}

// ---------------- final GEMM via MFMA: out = [x|A|B|C] @ W + bias -----------
// Block = 256 thr (4 waves) = 64 node rows. X staged as bf16 in LDS
// (stride 264 bf16 = 528 B: A-frag b128 reads land 2 lanes/bank-quad = free).
// W read from the 32 KB pre-transposed bf16 Wt[n][k] (B^T layout) straight
// from global (L1-resident). 8 k-steps x 4 n-tiles of mfma_f32_16x16x32_bf16.
// Layouts (verified, guide §3): A[m=lane&15][k=quad*8+j];
// D: col=lane&15, row=quad*4+reg.
#define XLD 264
__global__ __launch_bounds__(256) void final_gemm_mfma(
        const float4* __restrict__ x0,
        const float4* __restrict__ x1,
        const float4* __restrict__ x2,
        const ushort4* __restrict__ x3b,
        const unsigned short* __restrict__ Wt,
        const float* __restrict__ bias,
        float* __restrict__ out) {
    __shared__ unsigned short Xb[64 * XLD];
    const int tid = threadIdx.x;
    const int lane = tid & 63;
    const int w = tid >> 6;
    const int m = lane & 15;
    const int quad = lane >> 4;
    const int n0 = (int)blockIdx.x * 64;

    // stage 64 rows x K=256 as bf16 (segs 0..2 from fp32, seg 3 from bf16 Cb)
    #pragma unroll 1
    for (int seg = 0; seg < 4; ++seg) {
        #pragma unroll
        for (int j = 0; j < 4; ++j) {
            int idx = tid + 256 * j;          // 0..1023
            int r = idx >> 4, c4 = idx & 15;
            int gr = n0 + r;
            ushort4 hv;
            if (seg == 3) {
                hv = (gr < NN) ? x3b[(size_t)gr * 16 + c4] : make_ushort4(0, 0, 0, 0);
            } else {
                const float4* p = (seg == 0) ? x0 : (seg == 1) ? x1 : x2;
                float4 v = (gr < NN) ? p[(size_t)gr * 16 + c4]
                                     : make_float4(0.f, 0.f, 0.f, 0.f);
                hv.x = f2b(v.x); hv.y = f2b(v.y); hv.z = f2b(v.z); hv.w = f2b(v.w);
            }
            *(ushort4*)&Xb[r * XLD + seg * 64 + c4 * 4] = hv;
        }
    }
    __syncthreads();

    f32x4 acc[4];
    #pragma unroll
    for (int nt = 0; nt < 4; ++nt) acc[nt] = (f32x4){0.f, 0.f, 0.f, 0.f};

    #pragma unroll 1
    for (int ks = 0; ks < 8; ++ks) {
        short8 af = *(const short8*)&Xb[(16 * w + m) * XLD + ks * 32 + quad * 8];
        #pragma unroll
        for (int nt = 0; nt < 4; ++nt) {
            short8 bf = *(const short8*)&Wt[(nt * 16 + m) * 256 + ks * 32 + quad * 8];
            acc[nt] = __builtin_amdgcn_mfma_f32_16x16x32_bf16(af, bf, acc[nt], 0, 0, 0);
        }
    }

    // epilogue: D row = quad*4+reg (node), col = nt*16 + m (feature)
    #pragma unroll
    for (int nt = 0; nt < 4; ++nt) {
        float bv = bias[nt * 16 + m];
        #pragma unroll
        for (int rg = 0; rg < 4; ++rg) {
            int node = n0 + 16 * w + quad * 4 + rg;
            if (node < NN) out[(size_t)node * 64 + nt * 16 + m] = acc[nt][rg] + bv;
        }
    }
}

extern "C" void kernel_launch(void* const* d_in, const int* in_sizes, int n_in,
                              void* d_out, int out_size, void* d_ws, size_t ws_size,
                              hipStream_t stream) {
    const float* x  = (const float*)d_in[0];
    const int*   ei = (const int*)d_in[1];
    const float* ew = (const float*)d_in[2];
    const float* ap = (const float*)d_in[3];
    const float* lw = (const float*)d_in[4];
    const float* lb = (const float*)d_in[5];
    float* out = (float*)d_out;

    const int N = NN, E = EE;
    const int ND = N * DD;

    const int* row = ei;
    const int* col = ei + E;

    // workspace layout (16B-aligned):
    //  A fp32 | B fp32 | pool(Ab,Cb bf16) | ev | small
    char* ws = (char*)d_ws;
    float* A    = (float*)ws;                              // 25.6 MB
    float* B    = (float*)(ws + (size_t)ND * 4);           // 25.6 MB
    char*  pool = ws + (size_t)ND * 8;                     // 25.6 MB
    ushort4* Ab = (ushort4*)pool;                          // 12.8 MB
    ushort4* Cb = (ushort4*)(pool + (size_t)ND * 2);       // 12.8 MB
    float2* ev  = (float2*)(ws + (size_t)ND * 12);         // 10 MB
    char* sm    = ws + (size_t)ND * 12 + (size_t)E * 8;
    float* coef     = (float*)sm;                          // 256 B
    float* dis      = (float*)(sm + 256);                  // N floats
    int*   degi     = (int*)(sm + 256 + (size_t)N * 4);    // N ints (also cursor)
    int*   rowStart = (int*)(sm + 256 + (size_t)N * 8);    // N+1 ints
    int*   bs       = (int*)(sm + 256 + (size_t)N * 12 + 64);       // 512 ints
    unsigned short* Wt = (unsigned short*)(sm + 256 + (size_t)N * 12 + 64 + 4096); // 32 KB

    // bf16 overlays in d_out (both dead before final_gemm_mfma writes d_out):
    ushort4* xb = (ushort4*)d_out;                         // spmm1 gather src
    ushort4* Bb = (ushort4*)((char*)d_out + (size_t)ND * 2); // spmm3 gather src

    const int gridE  = (E + 255) / 256;      // 4883
    const int gridN  = (N + 255) / 256;      // 391
    const int gridSp = (N * 16) / 256;       // 6250 exact
    const int gridCv = (ND / 4) / 256;       // 6250 exact
    const int gridG  = (N + 63) / 64;        // 1563
    const int nChunk = (E + SCHUNK - 1) / SCHUNK;   // 611
    const int gridSc = nChunk * 8;                  // 4888

    // ---- CSR build ----
    hipMemsetAsync(degi, 0, (size_t)N * 4, stream);
    deg_count<<<gridE, 256, 0, stream>>>(row, degi, E);
    coef_kernel<<<1, 64, 0, stream>>>(ap, coef);
    wt_kernel<<<64, 256, 0, stream>>>(lw, Wt);
    scan_a<<<gridN, 256, 0, stream>>>(degi, rowStart, bs, N);
    scan_b<<<1, 512, 0, stream>>>(bs, gridN);
    scan_c<<<gridN, 256, 0, stream>>>(rowStart, bs, N, E);
    dis_kernel<<<gridN, 256, 0, stream>>>(degi, dis, N);
    hipMemsetAsync(degi, 0, (size_t)N * 4, stream);        // reuse as cursor
    scatter_sliced<<<gridSc, 256, 0, stream>>>(row, col, ew, dis, rowStart, degi, ev, E);

    // ---- bf16 copy of x for the L=1 gather ----
    tobf16<<<gridCv, 256, 0, stream>>>((const float4*)x, xb, ND / 4);

    // ---- L=1: A = c0*x + c1*(adj@x); emit Ab ----
    spmm_fused<0, 1, 1><<<gridSp, 256, 0, stream>>>(rowStart, ev, xb,
                                                    (const float4*)x, (const float4*)x,
                                                    (float4*)A, Ab, coef, 0, N);
    // ---- L=2: B = c0*(adj@A) - c1*A - c2*x; emit Bb ----
    spmm_fused<1, 1, 1><<<gridSp, 256, 0, stream>>>(rowStart, ev, Ab,
                                                    (const float4*)A, (const float4*)x,
                                                    (float4*)B, Bb, coef, 2, N);
    // ---- L=3: Cb(bf16 only) = c0*(adj@B) - c1*B - c2*A ----
    spmm_fused<1, 1, 0><<<gridSp, 256, 0, stream>>>(rowStart, ev, Bb,
                                                    (const float4*)B, (const float4*)A,
                                                    (float4*)nullptr, Cb, coef, 5, N);

    // ---- out = [x | A | B | C] @ W + b (MFMA) ----
    final_gemm_mfma<<<gridG, 256, 0, stream>>>((const float4*)x, (const float4*)A,
                                               (const float4*)B, Cb, Wt, lb, out);
}

// Round 9
// 355.454 us; speedup vs baseline: 7.8001x; 1.0458x over previous
//
#include <hip/hip_runtime.h>
#include <hip/hip_bf16.h>
#include <math.h>

#define NN 100000
#define EE 1250000
#define DD 64

typedef __attribute__((ext_vector_type(8))) short short8;
typedef __attribute__((ext_vector_type(4))) float f32x4;

// bf16 helpers (RNE)
__device__ __forceinline__ unsigned short f2b(float f) {
    unsigned u = __float_as_uint(f);
    u += 0x7fffu + ((u >> 16) & 1u);
    return (unsigned short)(u >> 16);
}
__device__ __forceinline__ float b2f(unsigned short h) {
    return __uint_as_float(((unsigned)h) << 16);
}

// ---------------- degree count (int atomics) ----------------
__global__ __launch_bounds__(256) void deg_count(const int* __restrict__ row,
                                                 int* __restrict__ degi, int E) {
    int e = blockIdx.x * 256 + threadIdx.x;
    if (e >= E) return;
    atomicAdd(&degi[row[e]], 1);
}

// ---------------- scan step A ----------------
__global__ __launch_bounds__(256) void scan_a(const int* __restrict__ degi,
                                              int* __restrict__ rowStart,
                                              int* __restrict__ bs, int N) {
    __shared__ int s[256];
    int tid = threadIdx.x;
    int i = blockIdx.x * 256 + tid;
    int v = (i < N) ? degi[i] : 0;
    s[tid] = v;
    __syncthreads();
    for (int off = 1; off < 256; off <<= 1) {
        int t = (tid >= off) ? s[tid - off] : 0;
        __syncthreads();
        s[tid] += t;
        __syncthreads();
    }
    if (i < N) rowStart[i] = s[tid] - v;   // exclusive
    if (tid == 255) bs[blockIdx.x] = s[255];
}

// ---------------- scan step B (1 block) ----------------
__global__ __launch_bounds__(512) void scan_b(int* __restrict__ bs, int nb) {
    __shared__ int s[512];
    int tid = threadIdx.x;
    int v = (tid < nb) ? bs[tid] : 0;
    s[tid] = v;
    __syncthreads();
    for (int off = 1; off < 512; off <<= 1) {
        int t = (tid >= off) ? s[tid - off] : 0;
        __syncthreads();
        s[tid] += t;
        __syncthreads();
    }
    if (tid < nb) bs[tid] = s[tid] - v;    // exclusive
}

// ---------------- scan step C ----------------
__global__ __launch_bounds__(256) void scan_c(int* __restrict__ rowStart,
                                              const int* __restrict__ bs,
                                              int N, int E) {
    int i = blockIdx.x * 256 + threadIdx.x;
    if (i < N) rowStart[i] += bs[blockIdx.x];
    if (i == 0) rowStart[N] = E;
}

// ---------------- dis = deg^-0.5 (deg==0 -> 1) ----------------
__global__ __launch_bounds__(256) void dis_kernel(const int* __restrict__ degi,
                                                  float* __restrict__ dis, int N) {
    int i = blockIdx.x * 256 + threadIdx.x;
    if (i >= N) return;
    int d = degi[i];
    float df = (d == 0) ? 1.0f : (float)d;
    dis[i] = 1.0f / sqrtf(df);
}

// ---------------- scatter edges into CSR order (unsliced; R8 slicing lost) ---
// WRITE_SIZE ~82 MB = one line-writeback per 8-B scattered store; slicing
// didn't fix it (streams evict the slice) and added 50 MB of re-reads.
__global__ __launch_bounds__(256) void scatter_kernel(const int* __restrict__ row,
                                                      const int* __restrict__ col,
                                                      const float* __restrict__ w,
                                                      const float* __restrict__ dis,
                                                      const int* __restrict__ rowStart,
                                                      int* __restrict__ cursor,
                                                      float2* __restrict__ ev, int E) {
    int e = blockIdx.x * 256 + threadIdx.x;
    if (e >= E) return;
    int r = row[e], c = col[e];
    int pos = rowStart[r] + atomicAdd(&cursor[r], 1);
    float v = dis[r] * w[e] * dis[c];
    ev[pos] = make_float2(v, __int_as_float(c));
}

// ---------------- scalar coefficients ----------------
__global__ void coef_kernel(const float* __restrict__ ap, float* __restrict__ coef) {
    if (threadIdx.x != 0 || blockIdx.x != 0) return;
    const float a = 1.0f, b = 1.0f, l = -1.0f, r = 1.0f;
    float als[3];
    als[0] = tanhf(ap[0]);
    als[1] = tanhf(ap[1]);
    als[2] = tanhf(ap[2]);
    float coef1 = (a - b) * 0.5f - (a + b + 2.0f) * 0.5f * ((l + r) / (r - l));
    float coef2 = (a + b + 2.0f) / (r - l);
    coef[0] = als[0] * coef1;
    coef[1] = als[0] * coef2;
    for (int L = 2; L <= 3; ++L) {
        float Lf = (float)L;
        float coef_l     = 2.0f * Lf * (Lf + a + b) * (2.0f * Lf - 2.0f + a + b);
        float coef_lm1_1 = (2.0f * Lf + a + b - 1.0f) * (2.0f * Lf + a + b) * (2.0f * Lf + a + b - 2.0f);
        float coef_lm1_2 = (2.0f * Lf + a + b - 1.0f) * (a * a - b * b);
        float coef_lm2   = 2.0f * (Lf - 1.0f + a) * (Lf - 1.0f + b) * (2.0f * Lf + a + b);
        float tmp1   = als[L - 1] * (coef_lm1_1 / coef_l);
        float tmp2   = als[L - 1] * (coef_lm1_2 / coef_l);
        float tmp3   = als[L - 1] * als[L - 2] * (coef_lm2 / coef_l);
        float tmp1_2 = tmp1 * (2.0f / (r - l));
        float tmp2_2 = tmp1 * ((r + l) / (r - l)) + tmp2;
        int base = 2 + (L - 2) * 3;
        coef[base + 0] = tmp1_2;
        coef[base + 1] = tmp2_2;
        coef[base + 2] = tmp3;
    }
}

// ---------------- fp32 -> bf16 copy ----------------
__global__ __launch_bounds__(256) void tobf16(const float4* __restrict__ in,
                                              ushort4* __restrict__ outb, int n4) {
    int i = blockIdx.x * 256 + threadIdx.x;
    if (i >= n4) return;
    float4 v = in[i];
    ushort4 o;
    o.x = f2b(v.x); o.y = f2b(v.y); o.z = f2b(v.z); o.w = f2b(v.w);
    outb[i] = o;
}

// ---------------- W transpose to bf16 [n][k] (B^T layout for MFMA) ----------
__global__ __launch_bounds__(256) void wt_kernel(const float* __restrict__ W,
                                                 unsigned short* __restrict__ Wt) {
    int idx = blockIdx.x * 256 + threadIdx.x;   // 0..16383
    int n = idx >> 8, k = idx & 255;
    Wt[idx] = f2b(W[k * 64 + n]);
}

// ---------------- fused CSR SpMM + combine, all-bf16 intermediates ----------
// 16 lanes per row. MODE 0: out = c0*m1 + c1*Ax; MODE 1: out = c0*Ax - c1*m1 - c2*m2
// All matrix I/O bf16 (halves streaming traffic vs fp32); fp32 accumulate.
template <int MODE>
__global__ __launch_bounds__(256) void spmm_fused(const int* __restrict__ rowStart,
                                                  const float2* __restrict__ ev,
                                                  const ushort4* __restrict__ hb,
                                                  const ushort4* __restrict__ xm1,
                                                  const ushort4* __restrict__ xm2,
                                                  ushort4* __restrict__ outb,
                                                  const float* __restrict__ coef,
                                                  int cbase, int N) {
    int t = blockIdx.x * 256 + threadIdx.x;
    int r = t >> 4;
    if (r >= N) return;
    int q = t & 15;
    int s0 = rowStart[r];
    int s1 = rowStart[r + 1];
    float4 acc = make_float4(0.f, 0.f, 0.f, 0.f);
    int j = s0;
    for (; j + 3 < s1; j += 4) {
        float2 e0 = ev[j];
        float2 e1 = ev[j + 1];
        float2 e2 = ev[j + 2];
        float2 e3 = ev[j + 3];
        ushort4 h0 = hb[(size_t)__float_as_int(e0.y) * 16 + q];
        ushort4 h1 = hb[(size_t)__float_as_int(e1.y) * 16 + q];
        ushort4 h2 = hb[(size_t)__float_as_int(e2.y) * 16 + q];
        ushort4 h3 = hb[(size_t)__float_as_int(e3.y) * 16 + q];
        acc.x += e0.x * b2f(h0.x) + e1.x * b2f(h1.x) + e2.x * b2f(h2.x) + e3.x * b2f(h3.x);
        acc.y += e0.x * b2f(h0.y) + e1.x * b2f(h1.y) + e2.x * b2f(h2.y) + e3.x * b2f(h3.y);
        acc.z += e0.x * b2f(h0.z) + e1.x * b2f(h1.z) + e2.x * b2f(h2.z) + e3.x * b2f(h3.z);
        acc.w += e0.x * b2f(h0.w) + e1.x * b2f(h1.w) + e2.x * b2f(h2.w) + e3.x * b2f(h3.w);
    }
    for (; j < s1; ++j) {
        float2 e0 = ev[j];
        ushort4 h0 = hb[(size_t)__float_as_int(e0.y) * 16 + q];
        acc.x += e0.x * b2f(h0.x);
        acc.y += e0.x * b2f(h0.y);
        acc.z += e0.x * b2f(h0.z);
        acc.w += e0.x * b2f(h0.w);
    }
    size_t oi = (size_t)r * 16 + q;
    float4 o;
    if (MODE == 0) {
        float c0 = coef[cbase], c1 = coef[cbase + 1];
        ushort4 m1 = xm1[oi];
        o.x = c0 * b2f(m1.x) + c1 * acc.x;
        o.y = c0 * b2f(m1.y) + c1 * acc.y;
        o.z = c0 * b2f(m1.z) + c1 * acc.z;
        o.w = c0 * b2f(m1.w) + c1 * acc.w;
    } else {
        float c0 = coef[cbase], c1 = coef[cbase + 1], c2 = coef[cbase + 2];
        ushort4 m1 = xm1[oi];
        ushort4 m2 = xm2[oi];
        o.x = c0 * acc.x - c1 * b2f(m1.x) - c2 * b2f(m2.x);
        o.y = c0 * acc.y - c1 * b2f(m1.y) - c2 * b2f(m2.y);
        o.z = c0 * acc.z - c1 * b2f(m1.z) - c2 * b2f(m2.z);
        o.w = c0 * acc.w - c1 * b2f(m1.w) - c2 * b2f(m2.w);
    }
    ushort4 ob;
    ob.x = f2b(o.x); ob.y = f2b(o.y); ob.z = f2b(o.z); ob.w = f2b(o.w);
    outb[oi] = ob;
}

// ---------------- final GEMM via MFMA: out = [x|A|B|C] @ W + bias -----------
// Block = 256 thr (4 waves) = 64 node rows. All four X segments bf16 in ws.
// LDS stride 264 bf16 (528 B): A-frag b128 reads 2 lanes/bank-quad = free.
// Wt = pre-transposed bf16 [n][k] (B^T) read from global (L1-resident).
// Layouts (verified): A[m=lane&15][k=quad*8+j]; D: col=lane&15, row=quad*4+reg.
#define XLD 264
__global__ __launch_bounds__(256) void final_gemm_mfma(
        const ushort4* __restrict__ x0,
        const ushort4* __restrict__ x1,
        const ushort4* __restrict__ x2,
        const ushort4* __restrict__ x3,
        const unsigned short* __restrict__ Wt,
        const float* __restrict__ bias,
        float* __restrict__ out) {
    __shared__ unsigned short Xb[64 * XLD];
    const int tid = threadIdx.x;
    const int lane = tid & 63;
    const int w = tid >> 6;
    const int m = lane & 15;
    const int quad = lane >> 4;
    const int n0 = (int)blockIdx.x * 64;

    #pragma unroll 1
    for (int seg = 0; seg < 4; ++seg) {
        const ushort4* p = (seg == 0) ? x0 : (seg == 1) ? x1 : (seg == 2) ? x2 : x3;
        #pragma unroll
        for (int j = 0; j < 4; ++j) {
            int idx = tid + 256 * j;          // 0..1023
            int r = idx >> 4, c4 = idx & 15;
            int gr = n0 + r;
            ushort4 hv = (gr < NN) ? p[(size_t)gr * 16 + c4] : make_ushort4(0, 0, 0, 0);
            *(ushort4*)&Xb[r * XLD + seg * 64 + c4 * 4] = hv;
        }
    }
    __syncthreads();

    f32x4 acc[4];
    #pragma unroll
    for (int nt = 0; nt < 4; ++nt) acc[nt] = (f32x4){0.f, 0.f, 0.f, 0.f};

    #pragma unroll 1
    for (int ks = 0; ks < 8; ++ks) {
        short8 af = *(const short8*)&Xb[(16 * w + m) * XLD + ks * 32 + quad * 8];
        #pragma unroll
        for (int nt = 0; nt < 4; ++nt) {
            short8 bf = *(const short8*)&Wt[(nt * 16 + m) * 256 + ks * 32 + quad * 8];
            acc[nt] = __builtin_amdgcn_mfma_f32_16x16x32_bf16(af, bf, acc[nt], 0, 0, 0);
        }
    }

    #pragma unroll
    for (int nt = 0; nt < 4; ++nt) {
        float bv = bias[nt * 16 + m];
        #pragma unroll
        for (int rg = 0; rg < 4; ++rg) {
            int node = n0 + 16 * w + quad * 4 + rg;
            if (node < NN) out[(size_t)node * 64 + nt * 16 + m] = acc[nt][rg] + bv;
        }
    }
}

extern "C" void kernel_launch(void* const* d_in, const int* in_sizes, int n_in,
                              void* d_out, int out_size, void* d_ws, size_t ws_size,
                              hipStream_t stream) {
    const float* x  = (const float*)d_in[0];
    const int*   ei = (const int*)d_in[1];
    const float* ew = (const float*)d_in[2];
    const float* ap = (const float*)d_in[3];
    const float* lw = (const float*)d_in[4];
    const float* lb = (const float*)d_in[5];
    float* out = (float*)d_out;

    const int N = NN, E = EE;
    const int ND = N * DD;

    const int* row = ei;
    const int* col = ei + E;

    // workspace layout (16B-aligned): xb | Ab | Bb | Cb (bf16) | ev | small
    char* ws = (char*)d_ws;
    ushort4* xb = (ushort4*)ws;                            // 12.8 MB
    ushort4* Ab = (ushort4*)(ws + (size_t)ND * 2);         // 12.8 MB
    ushort4* Bb = (ushort4*)(ws + (size_t)ND * 4);         // 12.8 MB
    ushort4* Cb = (ushort4*)(ws + (size_t)ND * 6);         // 12.8 MB
    float2* ev  = (float2*)(ws + (size_t)ND * 8);          // 10 MB
    char* sm    = ws + (size_t)ND * 8 + (size_t)E * 8;
    float* coef     = (float*)sm;                          // 256 B
    float* dis      = (float*)(sm + 256);                  // N floats
    int*   degi     = (int*)(sm + 256 + (size_t)N * 4);    // N ints (also cursor)
    int*   rowStart = (int*)(sm + 256 + (size_t)N * 8);    // N+1 ints
    int*   bs       = (int*)(sm + 256 + (size_t)N * 12 + 64);       // 512 ints
    unsigned short* Wt = (unsigned short*)(sm + 256 + (size_t)N * 12 + 64 + 4096); // 32 KB

    const int gridE  = (E + 255) / 256;      // 4883
    const int gridN  = (N + 255) / 256;      // 391
    const int gridSp = (N * 16) / 256;       // 6250 exact
    const int gridCv = (ND / 4) / 256;       // 6250 exact
    const int gridG  = (N + 63) / 64;        // 1563

    // ---- CSR build ----
    hipMemsetAsync(degi, 0, (size_t)N * 4, stream);
    deg_count<<<gridE, 256, 0, stream>>>(row, degi, E);
    coef_kernel<<<1, 64, 0, stream>>>(ap, coef);
    wt_kernel<<<64, 256, 0, stream>>>(lw, Wt);
    scan_a<<<gridN, 256, 0, stream>>>(degi, rowStart, bs, N);
    scan_b<<<1, 512, 0, stream>>>(bs, gridN);
    scan_c<<<gridN, 256, 0, stream>>>(rowStart, bs, N, E);
    dis_kernel<<<gridN, 256, 0, stream>>>(degi, dis, N);
    hipMemsetAsync(degi, 0, (size_t)N * 4, stream);        // reuse as cursor
    scatter_kernel<<<gridE, 256, 0, stream>>>(row, col, ew, dis, rowStart, degi, ev, E);

    // ---- bf16 copy of x ----
    tobf16<<<gridCv, 256, 0, stream>>>((const float4*)x, xb, ND / 4);

    // ---- L=1: Ab = c0*x + c1*(adj@x) ----
    spmm_fused<0><<<gridSp, 256, 0, stream>>>(rowStart, ev, xb, xb, xb,
                                              Ab, coef, 0, N);
    // ---- L=2: Bb = c0*(adj@A) - c1*A - c2*x ----
    spmm_fused<1><<<gridSp, 256, 0, stream>>>(rowStart, ev, Ab, Ab, xb,
                                              Bb, coef, 2, N);
    // ---- L=3: Cb = c0*(adj@B) - c1*B - c2*A ----
    spmm_fused<1><<<gridSp, 256, 0, stream>>>(rowStart, ev, Bb, Bb, Ab,
                                              Cb, coef, 5, N);

    // ---- out = [x | A | B | C] @ W + b (MFMA) ----
    final_gemm_mfma<<<gridG, 256, 0, stream>>>(xb, Ab, Bb, Cb, Wt, lb, out);
}

// Round 10
// 349.394 us; speedup vs baseline: 7.9354x; 1.0173x over previous
//
#include <hip/hip_runtime.h>
#include <hip/hip_bf16.h>
#include <math.h>

#define NN 100000
#define EE 1250000
#define DD 64

typedef __attribute__((ext_vector_type(8))) short short8;
typedef __attribute__((ext_vector_type(4))) float f32x4;

// bf16 helpers (RNE)
__device__ __forceinline__ unsigned short f2b(float f) {
    unsigned u = __float_as_uint(f);
    u += 0x7fffu + ((u >> 16) & 1u);
    return (unsigned short)(u >> 16);
}
__device__ __forceinline__ float b2f(unsigned short h) {
    return __uint_as_float(((unsigned)h) << 16);
}

// ---------------- degree count (int atomics) ----------------
__global__ __launch_bounds__(256) void deg_count(const int* __restrict__ row,
                                                 int* __restrict__ degi, int E) {
    int e = blockIdx.x * 256 + threadIdx.x;
    if (e >= E) return;
    atomicAdd(&degi[row[e]], 1);
}

// ---------------- scan step A ----------------
__global__ __launch_bounds__(256) void scan_a(const int* __restrict__ degi,
                                              int* __restrict__ rowStart,
                                              int* __restrict__ bs, int N) {
    __shared__ int s[256];
    int tid = threadIdx.x;
    int i = blockIdx.x * 256 + tid;
    int v = (i < N) ? degi[i] : 0;
    s[tid] = v;
    __syncthreads();
    for (int off = 1; off < 256; off <<= 1) {
        int t = (tid >= off) ? s[tid - off] : 0;
        __syncthreads();
        s[tid] += t;
        __syncthreads();
    }
    if (i < N) rowStart[i] = s[tid] - v;   // exclusive
    if (tid == 255) bs[blockIdx.x] = s[255];
}

// ---------------- scan step B (1 block) ----------------
__global__ __launch_bounds__(512) void scan_b(int* __restrict__ bs, int nb) {
    __shared__ int s[512];
    int tid = threadIdx.x;
    int v = (tid < nb) ? bs[tid] : 0;
    s[tid] = v;
    __syncthreads();
    for (int off = 1; off < 512; off <<= 1) {
        int t = (tid >= off) ? s[tid - off] : 0;
        __syncthreads();
        s[tid] += t;
        __syncthreads();
    }
    if (tid < nb) bs[tid] = s[tid] - v;    // exclusive
}

// ---------------- scan step C ----------------
__global__ __launch_bounds__(256) void scan_c(int* __restrict__ rowStart,
                                              const int* __restrict__ bs,
                                              int N, int E) {
    int i = blockIdx.x * 256 + threadIdx.x;
    if (i < N) rowStart[i] += bs[blockIdx.x];
    if (i == 0) rowStart[N] = E;
}

// ---------------- dis = deg^-0.5 (deg==0 -> 1) ----------------
__global__ __launch_bounds__(256) void dis_kernel(const int* __restrict__ degi,
                                                  float* __restrict__ dis, int N) {
    int i = blockIdx.x * 256 + threadIdx.x;
    if (i >= N) return;
    int d = degi[i];
    float df = (d == 0) ? 1.0f : (float)d;
    dis[i] = 1.0f / sqrtf(df);
}

// ---------------- scatter: CSR entries packed to 4 B ----------------
// val = dis_r*w*dis_c < 1 strictly -> 15-bit fixed point (abs err 1.5e-5,
// negligible vs bf16 h 0.4% rel). col needs 17 bits (N=100K). Pack
// (col<<15)|valq. Halving the payload halves the ~8x XCD line-writeback
// amplification (R9: WRITE 81 MB for 10 MB payload).
__global__ __launch_bounds__(256) void scatter_kernel(const int* __restrict__ row,
                                                      const int* __restrict__ col,
                                                      const float* __restrict__ w,
                                                      const float* __restrict__ dis,
                                                      const int* __restrict__ rowStart,
                                                      int* __restrict__ cursor,
                                                      unsigned* __restrict__ ev, int E) {
    int e = blockIdx.x * 256 + threadIdx.x;
    if (e >= E) return;
    int r = row[e], c = col[e];
    int pos = rowStart[r] + atomicAdd(&cursor[r], 1);
    float v = dis[r] * w[e] * dis[c];
    int vq = (int)(v * 32768.0f + 0.5f);
    vq = (vq > 32767) ? 32767 : vq;
    ev[pos] = ((unsigned)c << 15) | (unsigned)vq;
}

// ---------------- scalar coefficients ----------------
__global__ void coef_kernel(const float* __restrict__ ap, float* __restrict__ coef) {
    if (threadIdx.x != 0 || blockIdx.x != 0) return;
    const float a = 1.0f, b = 1.0f, l = -1.0f, r = 1.0f;
    float als[3];
    als[0] = tanhf(ap[0]);
    als[1] = tanhf(ap[1]);
    als[2] = tanhf(ap[2]);
    float coef1 = (a - b) * 0.5f - (a + b + 2.0f) * 0.5f * ((l + r) / (r - l));
    float coef2 = (a + b + 2.0f) / (r - l);
    coef[0] = als[0] * coef1;
    coef[1] = als[0] * coef2;
    for (int L = 2; L <= 3; ++L) {
        float Lf = (float)L;
        float coef_l     = 2.0f * Lf * (Lf + a + b) * (2.0f * Lf - 2.0f + a + b);
        float coef_lm1_1 = (2.0f * Lf + a + b - 1.0f) * (2.0f * Lf + a + b) * (2.0f * Lf + a + b - 2.0f);
        float coef_lm1_2 = (2.0f * Lf + a + b - 1.0f) * (a * a - b * b);
        float coef_lm2   = 2.0f * (Lf - 1.0f + a) * (Lf - 1.0f + b) * (2.0f * Lf + a + b);
        float tmp1   = als[L - 1] * (coef_lm1_1 / coef_l);
        float tmp2   = als[L - 1] * (coef_lm1_2 / coef_l);
        float tmp3   = als[L - 1] * als[L - 2] * (coef_lm2 / coef_l);
        float tmp1_2 = tmp1 * (2.0f / (r - l));
        float tmp2_2 = tmp1 * ((r + l) / (r - l)) + tmp2;
        int base = 2 + (L - 2) * 3;
        coef[base + 0] = tmp1_2;
        coef[base + 1] = tmp2_2;
        coef[base + 2] = tmp3;
    }
}

// ---------------- fp32 -> bf16 copy ----------------
__global__ __launch_bounds__(256) void tobf16(const float4* __restrict__ in,
                                              ushort4* __restrict__ outb, int n4) {
    int i = blockIdx.x * 256 + threadIdx.x;
    if (i >= n4) return;
    float4 v = in[i];
    ushort4 o;
    o.x = f2b(v.x); o.y = f2b(v.y); o.z = f2b(v.z); o.w = f2b(v.w);
    outb[i] = o;
}

// ---------------- W transpose to bf16 [n][k] (B^T layout for MFMA) ----------
__global__ __launch_bounds__(256) void wt_kernel(const float* __restrict__ W,
                                                 unsigned short* __restrict__ Wt) {
    int idx = blockIdx.x * 256 + threadIdx.x;   // 0..16383
    int n = idx >> 8, k = idx & 255;
    Wt[idx] = f2b(W[k * 64 + n]);
}

// ---------------- fused CSR SpMM + combine, all-bf16, packed ev -------------
// 16 lanes per row. MODE 0: out = c0*m1 + c1*Ax; MODE 1: out = c0*Ax - c1*m1 - c2*m2
// ev entry: (col<<15)|valq15. fp32 accumulate.
#define VSCL (1.0f / 32768.0f)
template <int MODE>
__global__ __launch_bounds__(256) void spmm_fused(const int* __restrict__ rowStart,
                                                  const unsigned* __restrict__ ev,
                                                  const ushort4* __restrict__ hb,
                                                  const ushort4* __restrict__ xm1,
                                                  const ushort4* __restrict__ xm2,
                                                  ushort4* __restrict__ outb,
                                                  const float* __restrict__ coef,
                                                  int cbase, int N) {
    int t = blockIdx.x * 256 + threadIdx.x;
    int r = t >> 4;
    if (r >= N) return;
    int q = t & 15;
    int s0 = rowStart[r];
    int s1 = rowStart[r + 1];
    float4 acc = make_float4(0.f, 0.f, 0.f, 0.f);
    int j = s0;
    for (; j + 3 < s1; j += 4) {
        unsigned u0 = ev[j];
        unsigned u1 = ev[j + 1];
        unsigned u2 = ev[j + 2];
        unsigned u3 = ev[j + 3];
        ushort4 h0 = hb[(size_t)(u0 >> 15) * 16 + q];
        ushort4 h1 = hb[(size_t)(u1 >> 15) * 16 + q];
        ushort4 h2 = hb[(size_t)(u2 >> 15) * 16 + q];
        ushort4 h3 = hb[(size_t)(u3 >> 15) * 16 + q];
        float v0 = (float)(u0 & 0x7fffu) * VSCL;
        float v1 = (float)(u1 & 0x7fffu) * VSCL;
        float v2 = (float)(u2 & 0x7fffu) * VSCL;
        float v3 = (float)(u3 & 0x7fffu) * VSCL;
        acc.x += v0 * b2f(h0.x) + v1 * b2f(h1.x) + v2 * b2f(h2.x) + v3 * b2f(h3.x);
        acc.y += v0 * b2f(h0.y) + v1 * b2f(h1.y) + v2 * b2f(h2.y) + v3 * b2f(h3.y);
        acc.z += v0 * b2f(h0.z) + v1 * b2f(h1.z) + v2 * b2f(h2.z) + v3 * b2f(h3.z);
        acc.w += v0 * b2f(h0.w) + v1 * b2f(h1.w) + v2 * b2f(h2.w) + v3 * b2f(h3.w);
    }
    for (; j < s1; ++j) {
        unsigned u0 = ev[j];
        ushort4 h0 = hb[(size_t)(u0 >> 15) * 16 + q];
        float v0 = (float)(u0 & 0x7fffu) * VSCL;
        acc.x += v0 * b2f(h0.x);
        acc.y += v0 * b2f(h0.y);
        acc.z += v0 * b2f(h0.z);
        acc.w += v0 * b2f(h0.w);
    }
    size_t oi = (size_t)r * 16 + q;
    float4 o;
    if (MODE == 0) {
        float c0 = coef[cbase], c1 = coef[cbase + 1];
        ushort4 m1 = xm1[oi];
        o.x = c0 * b2f(m1.x) + c1 * acc.x;
        o.y = c0 * b2f(m1.y) + c1 * acc.y;
        o.z = c0 * b2f(m1.z) + c1 * acc.z;
        o.w = c0 * b2f(m1.w) + c1 * acc.w;
    } else {
        float c0 = coef[cbase], c1 = coef[cbase + 1], c2 = coef[cbase + 2];
        ushort4 m1 = xm1[oi];
        ushort4 m2 = xm2[oi];
        o.x = c0 * acc.x - c1 * b2f(m1.x) - c2 * b2f(m2.x);
        o.y = c0 * acc.y - c1 * b2f(m1.y) - c2 * b2f(m2.y);
        o.z = c0 * acc.z - c1 * b2f(m1.z) - c2 * b2f(m2.z);
        o.w = c0 * acc.w - c1 * b2f(m1.w) - c2 * b2f(m2.w);
    }
    ushort4 ob;
    ob.x = f2b(o.x); ob.y = f2b(o.y); ob.z = f2b(o.z); ob.w = f2b(o.w);
    outb[oi] = ob;
}

// ---------------- final GEMM via MFMA: out = [x|A|B|C] @ W + bias -----------
// Block = 256 thr (4 waves) = 64 node rows. All four X segments bf16 in ws.
// LDS stride 264 bf16 (528 B): A-frag b128 reads 2 lanes/bank-quad = free.
// Wt = pre-transposed bf16 [n][k] (B^T) read from global (L1-resident).
// Layouts (verified): A[m=lane&15][k=quad*8+j]; D: col=lane&15, row=quad*4+reg.
#define XLD 264
__global__ __launch_bounds__(256) void final_gemm_mfma(
        const ushort4* __restrict__ x0,
        const ushort4* __restrict__ x1,
        const ushort4* __restrict__ x2,
        const ushort4* __restrict__ x3,
        const unsigned short* __restrict__ Wt,
        const float* __restrict__ bias,
        float* __restrict__ out) {
    __shared__ unsigned short Xb[64 * XLD];
    const int tid = threadIdx.x;
    const int lane = tid & 63;
    const int w = tid >> 6;
    const int m = lane & 15;
    const int quad = lane >> 4;
    const int n0 = (int)blockIdx.x * 64;

    #pragma unroll 1
    for (int seg = 0; seg < 4; ++seg) {
        const ushort4* p = (seg == 0) ? x0 : (seg == 1) ? x1 : (seg == 2) ? x2 : x3;
        #pragma unroll
        for (int j = 0; j < 4; ++j) {
            int idx = tid + 256 * j;          // 0..1023
            int r = idx >> 4, c4 = idx & 15;
            int gr = n0 + r;
            ushort4 hv = (gr < NN) ? p[(size_t)gr * 16 + c4] : make_ushort4(0, 0, 0, 0);
            *(ushort4*)&Xb[r * XLD + seg * 64 + c4 * 4] = hv;
        }
    }
    __syncthreads();

    f32x4 acc[4];
    #pragma unroll
    for (int nt = 0; nt < 4; ++nt) acc[nt] = (f32x4){0.f, 0.f, 0.f, 0.f};

    #pragma unroll 1
    for (int ks = 0; ks < 8; ++ks) {
        short8 af = *(const short8*)&Xb[(16 * w + m) * XLD + ks * 32 + quad * 8];
        #pragma unroll
        for (int nt = 0; nt < 4; ++nt) {
            short8 bf = *(const short8*)&Wt[(nt * 16 + m) * 256 + ks * 32 + quad * 8];
            acc[nt] = __builtin_amdgcn_mfma_f32_16x16x32_bf16(af, bf, acc[nt], 0, 0, 0);
        }
    }

    #pragma unroll
    for (int nt = 0; nt < 4; ++nt) {
        float bv = bias[nt * 16 + m];
        #pragma unroll
        for (int rg = 0; rg < 4; ++rg) {
            int node = n0 + 16 * w + quad * 4 + rg;
            if (node < NN) out[(size_t)node * 64 + nt * 16 + m] = acc[nt][rg] + bv;
        }
    }
}

extern "C" void kernel_launch(void* const* d_in, const int* in_sizes, int n_in,
                              void* d_out, int out_size, void* d_ws, size_t ws_size,
                              hipStream_t stream) {
    const float* x  = (const float*)d_in[0];
    const int*   ei = (const int*)d_in[1];
    const float* ew = (const float*)d_in[2];
    const float* ap = (const float*)d_in[3];
    const float* lw = (const float*)d_in[4];
    const float* lb = (const float*)d_in[5];
    float* out = (float*)d_out;

    const int N = NN, E = EE;
    const int ND = N * DD;

    const int* row = ei;
    const int* col = ei + E;

    // workspace layout (16B-aligned): xb | Ab | Bb | Cb (bf16) | ev(4B) | small
    char* ws = (char*)d_ws;
    ushort4* xb = (ushort4*)ws;                            // 12.8 MB
    ushort4* Ab = (ushort4*)(ws + (size_t)ND * 2);         // 12.8 MB
    ushort4* Bb = (ushort4*)(ws + (size_t)ND * 4);         // 12.8 MB
    ushort4* Cb = (ushort4*)(ws + (size_t)ND * 6);         // 12.8 MB
    unsigned* ev = (unsigned*)(ws + (size_t)ND * 8);       // 5 MB
    char* sm    = ws + (size_t)ND * 8 + (size_t)E * 4;
    float* coef     = (float*)sm;                          // 256 B
    float* dis      = (float*)(sm + 256);                  // N floats
    int*   degi     = (int*)(sm + 256 + (size_t)N * 4);    // N ints (also cursor)
    int*   rowStart = (int*)(sm + 256 + (size_t)N * 8);    // N+1 ints
    int*   bs       = (int*)(sm + 256 + (size_t)N * 12 + 64);       // 512 ints
    unsigned short* Wt = (unsigned short*)(sm + 256 + (size_t)N * 12 + 64 + 4096); // 32 KB

    const int gridE  = (E + 255) / 256;      // 4883
    const int gridN  = (N + 255) / 256;      // 391
    const int gridSp = (N * 16) / 256;       // 6250 exact
    const int gridCv = (ND / 4) / 256;       // 6250 exact
    const int gridG  = (N + 63) / 64;        // 1563

    // ---- CSR build ----
    hipMemsetAsync(degi, 0, (size_t)N * 4, stream);
    deg_count<<<gridE, 256, 0, stream>>>(row, degi, E);
    coef_kernel<<<1, 64, 0, stream>>>(ap, coef);
    wt_kernel<<<64, 256, 0, stream>>>(lw, Wt);
    scan_a<<<gridN, 256, 0, stream>>>(degi, rowStart, bs, N);
    scan_b<<<1, 512, 0, stream>>>(bs, gridN);
    scan_c<<<gridN, 256, 0, stream>>>(rowStart, bs, N, E);
    dis_kernel<<<gridN, 256, 0, stream>>>(degi, dis, N);
    hipMemsetAsync(degi, 0, (size_t)N * 4, stream);        // reuse as cursor
    scatter_kernel<<<gridE, 256, 0, stream>>>(row, col, ew, dis, rowStart, degi, ev, E);

    // ---- bf16 copy of x ----
    tobf16<<<gridCv, 256, 0, stream>>>((const float4*)x, xb, ND / 4);

    // ---- L=1: Ab = c0*x + c1*(adj@x) ----
    spmm_fused<0><<<gridSp, 256, 0, stream>>>(rowStart, ev, xb, xb, xb,
                                              Ab, coef, 0, N);
    // ---- L=2: Bb = c0*(adj@A) - c1*A - c2*x ----
    spmm_fused<1><<<gridSp, 256, 0, stream>>>(rowStart, ev, Ab, Ab, xb,
                                              Bb, coef, 2, N);
    // ---- L=3: Cb = c0*(adj@B) - c1*B - c2*A ----
    spmm_fused<1><<<gridSp, 256, 0, stream>>>(rowStart, ev, Bb, Bb, Ab,
                                              Cb, coef, 5, N);

    // ---- out = [x | A | B | C] @ W + b (MFMA) ----
    final_gemm_mfma<<<gridG, 256, 0, stream>>>(xb, Ab, Bb, Cb, Wt, lb, out);
}